// Round 6
// baseline (559.730 us; speedup 1.0000x reference)
//
#include <hip/hip_runtime.h>
#include <hip/hip_bf16.h>
#include <math.h>

typedef __hip_bfloat16 bf16;

#define FEAT 128
#define NRBF 20
#define CUTOFF_F 5.0f
#define KSCALE 0.62831853071795864769f  // pi / 5

__device__ __forceinline__ float b2f(bf16 x) { return __bfloat162float(x); }
__device__ __forceinline__ bf16 f2b(float x) { return __float2bfloat16(x); }

template<int F32>
__device__ __forceinline__ float LD(const void* p, size_t i) {
    if (F32) return ((const float*)p)[i];
    return b2f(((const bf16*)p)[i]);
}
template<int F32>
__device__ __forceinline__ void ST(void* p, size_t i, float v) {
    if (F32) ((float*)p)[i] = v;
    else ((bf16*)p)[i] = f2b(v);
}

__device__ __forceinline__ int get_dst(const int* nb, int e, int is64) {
    return is64 ? nb[4 * e] : nb[2 * e];
}
__device__ __forceinline__ int get_src(const int* nb, int e, int is64) {
    return is64 ? nb[4 * e + 2] : nb[2 * e + 1];
}
__device__ __forceinline__ int clampi(int v, int n) {
    return v < 0 ? 0 : (v >= n ? n - 1 : v);
}

// ---------- init: zero counts + sniff dtypes ----------
__global__ void init_kernel(const void* __restrict__ s_ptr, const int* __restrict__ nbrs32,
                            int nE, int* __restrict__ flags, int* __restrict__ counts, int nN) {
    int t = blockIdx.x * blockDim.x + threadIdx.x;
    if (t < nN) counts[t] = 0;
    if (t == 0) {
        const unsigned* u = (const unsigned*)s_ptr;
        int hits = 0;
        for (int i = 0; i < 64; ++i) {
            unsigned ef = (u[i] >> 7) & 0xFF;
            hits += (ef >= 110 && ef <= 135) ? 1 : 0;
        }
        flags[0] = (hits < 32) ? 1 : 0;   // 1 => f32 inputs
        int lim = 2 * nE; if (lim > 128) lim = 128;
        int allz = 1;
        for (int i = 1; i < lim; i += 2) allz &= (nbrs32[i] == 0);
        flags[1] = allz;                   // 1 => int64 nbrs
    }
}

// ---------- CSR build ----------
__global__ void hist_kernel(const int* __restrict__ nbrs, const int* __restrict__ flags,
                            int* __restrict__ counts, int nE, int nN) {
    int e = blockIdx.x * blockDim.x + threadIdx.x;
    if (e < nE) {
        int d = clampi(get_dst(nbrs, e, flags[1]), nN);
        atomicAdd(&counts[d], 1);
    }
}

__global__ __launch_bounds__(1024) void scan_kernel(const int* __restrict__ counts,
        int* __restrict__ offsets, int* __restrict__ cursor, int nN) {
    __shared__ int part[1024];
    const int t = threadIdx.x;
    const int chunk = (nN + 1023) / 1024;
    const int base = t * chunk;
    int local[32];
    int sum = 0;
    for (int c = 0; c < chunk && c < 32; ++c) {
        int idx = base + c;
        int v = (idx < nN) ? counts[idx] : 0;
        local[c] = v;
        sum += v;
    }
    part[t] = sum;
    __syncthreads();
    for (int off = 1; off < 1024; off <<= 1) {
        int add = (t >= off) ? part[t - off] : 0;
        __syncthreads();
        part[t] += add;
        __syncthreads();
    }
    int run = part[t] - sum;
    for (int c = 0; c < chunk && c < 32; ++c) {
        int idx = base + c;
        if (idx < nN) { offsets[idx] = run; cursor[idx] = run; run += local[c]; }
    }
    if (t == 1023) offsets[nN] = part[1023];
}

// ---------- prep: WdT[c][0..19] = Wd[k][c] (f32), WdT[c][20] = bd[c]; rows padded to 24 ----------
__global__ __launch_bounds__(384) void prep_kernel(const void* __restrict__ Wd,
        const void* __restrict__ bd, float* __restrict__ WdT, const int* __restrict__ flags) {
    const int c = threadIdx.x;
    const int F32 = flags[0];
    if (F32) {
        for (int k = 0; k < NRBF; ++k) WdT[c * 24 + k] = ((const float*)Wd)[k * 384 + c];
        WdT[c * 24 + 20] = ((const float*)bd)[c];
    } else {
        for (int k = 0; k < NRBF; ++k) WdT[c * 24 + k] = b2f(((const bf16*)Wd)[k * 384 + c]);
        WdT[c * 24 + 20] = b2f(((const bf16*)bd)[c]);
    }
    WdT[c * 24 + 21] = 0.f; WdT[c * 24 + 22] = 0.f; WdT[c * 24 + 23] = 0.f;
}

// ---------- scatter phase ----------
// MODE 0 (B): src_ids + u_env + gbuf (trig here)
// MODE 1 (A): src_ids + u_env + pos_of_e (trig here)
// MODE 2 (C): src_ids + edge_of_pos ONLY (8B/edge scattered; trig deferred to finalize)
template<int F32, int MODE>
__device__ void pre_scatter_body(const void* __restrict__ r_ij, const int* __restrict__ nbrs,
        int is64, int* __restrict__ cursor, int* __restrict__ src_ids,
        float4* __restrict__ u_env, int* __restrict__ pos_of_e, float* __restrict__ gbuf,
        int* __restrict__ edge_of_pos, int e, int nE, int nN) {
    const int d = clampi(get_dst(nbrs, e, is64), nN);
    const int j = clampi(get_src(nbrs, e, is64), nN);
    int pos = atomicAdd(&cursor[d], 1);
    pos = clampi(pos, nE);
    src_ids[pos] = j;

    if (MODE == 2) {
        edge_of_pos[pos] = e;
        return;
    }

    const float rx = LD<F32>(r_ij, (size_t)3 * e + 0);
    const float ry = LD<F32>(r_ij, (size_t)3 * e + 1);
    const float rz = LD<F32>(r_ij, (size_t)3 * e + 2);
    const float d2   = rx * rx + ry * ry + rz * rz + 3e-15f;
    const float invd = rsqrtf(d2);
    const float dd   = d2 * invd;
    const float x  = dd * KSCALE;
    const float c1 = F32 ? cosf(x) : __cosf(x);
    const float env = (dd < CUTOFF_F) ? (0.5f * (c1 + 1.0f)) : 0.0f;
    u_env[pos] = make_float4(rx * invd, ry * invd, rz * invd, env);

    if (MODE == 1) {
        pos_of_e[e] = pos;
    } else {
        const float s1 = F32 ? sinf(x) : __sinf(x);
        const float scale = invd * env;
        const float tc = 2.0f * c1;
        float skm2 = 0.f, skm1 = s1;
        float* g = gbuf + (size_t)pos * NRBF;
        g[0] = s1 * scale;
        #pragma unroll
        for (int k = 1; k < NRBF; ++k) {
            const float sk = fmaf(tc, skm1, -skm2);
            g[k] = sk * scale;
            skm2 = skm1; skm1 = sk;
        }
    }
}

__global__ __launch_bounds__(256) void pre_scatter_kernel(const void* r_ij, const int* nbrs,
        const int* __restrict__ flags, int* cursor, int* src_ids, float4* u_env,
        int* pos_of_e, float* gbuf, int* edge_of_pos, int nE, int nN, int mode) {
    int e = blockIdx.x * blockDim.x + threadIdx.x;
    if (e >= nE) return;
    const int F32 = flags[0], is64 = flags[1];
    if (mode == 2) {
        if (F32) pre_scatter_body<1,2>(r_ij, nbrs, is64, cursor, src_ids, u_env, pos_of_e, gbuf, edge_of_pos, e, nE, nN);
        else     pre_scatter_body<0,2>(r_ij, nbrs, is64, cursor, src_ids, u_env, pos_of_e, gbuf, edge_of_pos, e, nE, nN);
    } else if (mode == 1) {
        if (F32) pre_scatter_body<1,1>(r_ij, nbrs, is64, cursor, src_ids, u_env, pos_of_e, gbuf, edge_of_pos, e, nE, nN);
        else     pre_scatter_body<0,1>(r_ij, nbrs, is64, cursor, src_ids, u_env, pos_of_e, gbuf, edge_of_pos, e, nE, nN);
    } else {
        if (F32) pre_scatter_body<1,0>(r_ij, nbrs, is64, cursor, src_ids, u_env, pos_of_e, gbuf, edge_of_pos, e, nE, nN);
        else     pre_scatter_body<0,0>(r_ij, nbrs, is64, cursor, src_ids, u_env, pos_of_e, gbuf, edge_of_pos, e, nE, nN);
    }
}

// ---------- mode C finalize: coalesced over pos; random (cached) r_ij read ----------
template<int F32>
__device__ void finalize_body(const void* __restrict__ r_ij, const int* __restrict__ edge_of_pos,
        float4* __restrict__ u_env, float* __restrict__ gbuf, int t, int nE) {
    const int e = clampi(edge_of_pos[t], nE);
    const float rx = LD<F32>(r_ij, (size_t)3 * e + 0);
    const float ry = LD<F32>(r_ij, (size_t)3 * e + 1);
    const float rz = LD<F32>(r_ij, (size_t)3 * e + 2);
    const float d2   = rx * rx + ry * ry + rz * rz + 3e-15f;
    const float invd = rsqrtf(d2);
    const float dd   = d2 * invd;
    const float x  = dd * KSCALE;
    const float c1 = F32 ? cosf(x) : __cosf(x);
    const float s1 = F32 ? sinf(x) : __sinf(x);
    const float env = (dd < CUTOFF_F) ? (0.5f * (c1 + 1.0f)) : 0.0f;
    u_env[t] = make_float4(rx * invd, ry * invd, rz * invd, env);

    const float scale = invd * env;
    const float tc = 2.0f * c1;
    float g[NRBF];
    float skm2 = 0.f, skm1 = s1;
    g[0] = s1 * scale;
    #pragma unroll
    for (int k = 1; k < NRBF; ++k) {
        const float sk = fmaf(tc, skm1, -skm2);
        g[k] = sk * scale;
        skm2 = skm1; skm1 = sk;
    }
    float4* gd = (float4*)(gbuf + (size_t)t * NRBF);
    #pragma unroll
    for (int q = 0; q < 5; ++q)
        gd[q] = make_float4(g[4*q], g[4*q+1], g[4*q+2], g[4*q+3]);
}

__global__ __launch_bounds__(256) void finalize_kernel(const void* r_ij,
        const int* __restrict__ edge_of_pos, float4* __restrict__ u_env,
        float* __restrict__ gbuf, const int* __restrict__ flags, int nE) {
    int t = blockIdx.x * blockDim.x + threadIdx.x;
    if (t >= nE) return;
    if (flags[0]) finalize_body<1>(r_ij, edge_of_pos, u_env, gbuf, t, nE);
    else          finalize_body<0>(r_ij, edge_of_pos, u_env, gbuf, t, nE);
}

// ---------- fused node MLP: phi = silu(s@W1+b1)@W2 + b2 ----------
template<int F32>
__device__ void gemm_body(const void* __restrict__ s_j, const void* __restrict__ W1,
                          const void* __restrict__ b1, const void* __restrict__ W2,
                          const void* __restrict__ b2v, bf16* __restrict__ phi, int nN,
                          int packed) {
    __shared__ float sl[8][FEAT];
    __shared__ float hl[8][FEAT];
    const int t = threadIdx.x;
    const int n0 = blockIdx.x * 8;
    for (int idx = t; idx < 8 * FEAT; idx += 384) {
        int n = idx >> 7, k = idx & 127;
        int row = n0 + n;
        sl[n][k] = (row < nN) ? LD<F32>(s_j, (size_t)row * FEAT + k) : 0.f;
    }
    __syncthreads();
    for (int idx = t; idx < 8 * FEAT; idx += 384) {
        int n = idx >> 7, f = idx & 127;
        float a = 0.f;
        #pragma unroll 4
        for (int k = 0; k < FEAT; ++k) a = fmaf(sl[n][k], LD<F32>(W1, (size_t)k * FEAT + f), a);
        a += LD<F32>(b1, f);
        float sg = F32 ? (1.0f / (1.0f + expf(-a))) : (1.0f / (1.0f + __expf(-a)));
        hl[n][f] = a * sg;
    }
    __syncthreads();
    float acc[8] = {};
    #pragma unroll 4
    for (int k = 0; k < FEAT; ++k) {
        const float w = LD<F32>(W2, (size_t)k * 384 + t);
        #pragma unroll
        for (int n = 0; n < 8; ++n) acc[n] = fmaf(hl[n][k], w, acc[n]);
    }
    const float bb = LD<F32>(b2v, t);
    const int fch  = t & 127;
    const int comp = t >> 7;
    #pragma unroll
    for (int n = 0; n < 8; ++n) {
        int row = n0 + n;
        if (row < nN) {
            if (packed) phi[((size_t)row * FEAT + fch) * 8 + comp] = f2b(acc[n] + bb);
            else        phi[(size_t)row * 384 + t] = f2b(acc[n] + bb);
        }
    }
}

__global__ __launch_bounds__(384) void gemm_node_kernel(const void* s_j, const void* W1,
        const void* b1, const void* W2, const void* b2v, bf16* phi,
        const int* __restrict__ flags, int nN, int packed) {
    if (flags[0]) gemm_body<1>(s_j, W1, b1, W2, b2v, phi, nN, packed);
    else          gemm_body<0>(s_j, W1, b1, W2, b2v, phi, nN, packed);
}

// ---------- mode C: pack v_j (->bf16) into rec slots 4..6 ----------
__global__ __launch_bounds__(256) void pack_v_kernel(const void* __restrict__ v_j,
        bf16* __restrict__ rec, const int* __restrict__ flags, int nN) {
    int t = blockIdx.x * blockDim.x + threadIdx.x;   // t over nN*FEAT
    if (t >= nN * FEAT) return;
    float vx, vy, vz;
    if (flags[0]) {
        const float* v = (const float*)v_j;
        vx = v[(size_t)3 * t + 0];
        vy = v[(size_t)3 * t + 1];
        vz = v[(size_t)3 * t + 2];
    } else {
        const bf16* v = (const bf16*)v_j;
        vx = b2f(v[(size_t)3 * t + 0]);
        vy = b2f(v[(size_t)3 * t + 1]);
        vz = b2f(v[(size_t)3 * t + 2]);
    }
    bf16* d = rec + (size_t)t * 8;
    union { bf16 b[2]; unsigned u; } p01;
    p01.b[0] = f2b(vx); p01.b[1] = f2b(vy);
    *(unsigned*)(d + 4) = p01.u;     // byte offset 8, 4-aligned
    d[6] = f2b(vz);
}

// ---------- mode A: per-edge w_s GEMM ----------
template<int F32>
__device__ void pre_ws_body(const void* __restrict__ r_ij, const float* __restrict__ WdT,
        const int* __restrict__ pos_of_e, bf16* __restrict__ ws_w, int e) {
    const float rx = LD<F32>(r_ij, (size_t)3 * e + 0);
    const float ry = LD<F32>(r_ij, (size_t)3 * e + 1);
    const float rz = LD<F32>(r_ij, (size_t)3 * e + 2);
    const float d2   = rx * rx + ry * ry + rz * rz + 3e-15f;
    const float invd = rsqrtf(d2);
    const float dd   = d2 * invd;
    const float x  = dd * KSCALE;
    const float s1 = F32 ? sinf(x) : __sinf(x);
    const float c1 = F32 ? cosf(x) : __cosf(x);
    const float env = (dd < CUTOFF_F) ? (0.5f * (c1 + 1.0f)) : 0.0f;
    const float scale = invd * env;
    float gk[NRBF];
    const float tc = 2.0f * c1;
    float skm2 = 0.f, skm1 = s1;
    gk[0] = s1 * scale;
    #pragma unroll
    for (int k = 1; k < NRBF; ++k) {
        const float sk = fmaf(tc, skm1, -skm2);
        gk[k] = sk * scale;
        skm2 = skm1; skm1 = sk;
    }
    const int pos = pos_of_e[e];
    bf16* dst = ws_w + (size_t)pos * 384;
    for (int c0 = 0; c0 < 384; c0 += 4) {
        float r[4];
        #pragma unroll
        for (int u = 0; u < 4; ++u) {
            const float* w = WdT + (size_t)(c0 + u) * 24;
            float acc = w[20] * env;
            #pragma unroll
            for (int k = 0; k < NRBF; ++k) acc = fmaf(gk[k], w[k], acc);
            r[u] = acc;
        }
        union { bf16 b[4]; uint2 u2; } pk;
        pk.b[0] = f2b(r[0]); pk.b[1] = f2b(r[1]); pk.b[2] = f2b(r[2]); pk.b[3] = f2b(r[3]);
        *(uint2*)(dst + c0) = pk.u2;
    }
}

__global__ __launch_bounds__(256) void pre_ws_kernel(const void* r_ij,
        const float* __restrict__ WdT, const int* __restrict__ pos_of_e,
        bf16* __restrict__ ws_w, const int* __restrict__ flags, int nE) {
    int e = blockIdx.x * blockDim.x + threadIdx.x;
    if (e >= nE) return;
    if (flags[0]) pre_ws_body<1>(r_ij, WdT, pos_of_e, ws_w, e);
    else          pre_ws_body<0>(r_ij, WdT, pos_of_e, ws_w, e);
}

// ---------- mode A message: pure gather-accumulate ----------
template<int F32>
__device__ void msg_a_body(const bf16* __restrict__ ws_w, const bf16* __restrict__ phi,
        const void* __restrict__ v_j, const int* __restrict__ src_ids,
        const float4* __restrict__ u_env, const int* __restrict__ offsets,
        void* __restrict__ out, int nE, int nN) {
    const int i = blockIdx.x;
    const int f = threadIdx.x;
    int start = offsets[i];
    int end   = offsets[i + 1];
    if (start < 0) start = 0;
    if (end > nE) end = nE;

    float ds = 0.f, dv0 = 0.f, dv1 = 0.f, dv2 = 0.f;

    #pragma unroll 2
    for (int p = start; p < end; ++p) {
        const int j = src_ids[p];
        const float4 ue = u_env[p];
        const bf16* wr = ws_w + (size_t)p * 384;
        const float w0 = b2f(wr[f]);
        const float w1 = b2f(wr[FEAT + f]);
        const float w2 = b2f(wr[2 * FEAT + f]);
        const bf16* ph = phi + (size_t)j * 384;
        const float p0 = b2f(ph[f]);
        const float p1 = b2f(ph[FEAT + f]);
        const float p2 = b2f(ph[2 * FEAT + f]);
        const float vx = LD<F32>(v_j, ((size_t)j * FEAT + f) * 3 + 0);
        const float vy = LD<F32>(v_j, ((size_t)j * FEAT + f) * 3 + 1);
        const float vz = LD<F32>(v_j, ((size_t)j * FEAT + f) * 3 + 2);
        const float i0 = w0 * p0;
        const float i1 = w1 * p1;
        const float i2 = w2 * p2;
        ds += i1;
        dv0 = fmaf(i2, ue.x, fmaf(i0, vx, dv0));
        dv1 = fmaf(i2, ue.y, fmaf(i0, vy, dv1));
        dv2 = fmaf(i2, ue.z, fmaf(i0, vz, dv2));
    }

    ST<F32>(out, (size_t)i * FEAT + f, ds);
    const size_t ob = (size_t)nN * FEAT + ((size_t)i * FEAT + f) * 3;
    ST<F32>(out, ob + 0, dv0);
    ST<F32>(out, ob + 1, dv1);
    ST<F32>(out, ob + 2, dv2);
}

__global__ __launch_bounds__(128) void msg_a_kernel(const bf16* ws_w, const bf16* phi,
        const void* v_j, const int* src_ids, const float4* u_env, const int* offsets,
        const int* __restrict__ flags, void* out, int nE, int nN) {
    if (flags[0]) msg_a_body<1>(ws_w, phi, v_j, src_ids, u_env, offsets, out, nE, nN);
    else          msg_a_body<0>(ws_w, phi, v_j, src_ids, u_env, offsets, out, nE, nN);
}

// ---------- mode C message: weights hoisted as float4 regs; bounds (128,2) ----------
// R5/R6: 63 weight floats held in VGPRs (static indexing, no pin). (128,2) lifts the
// VGPR cap to 256; ~110 VGPR still permits 4 waves/EU (= current 50% occupancy).
template<int F32>
__device__ void msg_c_body(const float* __restrict__ WdT, const bf16* __restrict__ rec,
        const float* __restrict__ gbuf, const int* __restrict__ src_ids,
        const float4* __restrict__ u_env, const int* __restrict__ offsets,
        void* __restrict__ out, int nE, int nN) {
    const int i = blockIdx.x;
    const int f = threadIdx.x;
    int start = offsets[i];
    int end   = offsets[i + 1];
    if (start < 0) start = 0;
    if (end > nE) end = nE;

    const float4* wq0 = (const float4*)(WdT + (size_t)f * 24);
    const float4* wq1 = (const float4*)(WdT + (size_t)(f + FEAT) * 24);
    const float4* wq2 = (const float4*)(WdT + (size_t)(f + 2 * FEAT) * 24);
    float4 A0[5], A1[5], A2[5];
    #pragma unroll
    for (int q = 0; q < 5; ++q) { A0[q] = wq0[q]; A1[q] = wq1[q]; A2[q] = wq2[q]; }
    const float B0 = WdT[(size_t)f * 24 + 20];
    const float B1 = WdT[(size_t)(f + FEAT) * 24 + 20];
    const float B2 = WdT[(size_t)(f + 2 * FEAT) * 24 + 20];

    float ds = 0.f, dv0 = 0.f, dv1 = 0.f, dv2 = 0.f;

    for (int p = start; p < end; ++p) {
        const int j = src_ids[p];
        const float4 ue = u_env[p];
        const float4* g4 = (const float4*)(gbuf + (size_t)p * NRBF);
        float t0 = 0.f, t1 = 0.f, t2 = 0.f;
        #pragma unroll
        for (int q = 0; q < 5; ++q) {
            const float4 gq = g4[q];
            t0 = fmaf(gq.x, A0[q].x, t0); t0 = fmaf(gq.y, A0[q].y, t0);
            t0 = fmaf(gq.z, A0[q].z, t0); t0 = fmaf(gq.w, A0[q].w, t0);
            t1 = fmaf(gq.x, A1[q].x, t1); t1 = fmaf(gq.y, A1[q].y, t1);
            t1 = fmaf(gq.z, A1[q].z, t1); t1 = fmaf(gq.w, A1[q].w, t1);
            t2 = fmaf(gq.x, A2[q].x, t2); t2 = fmaf(gq.y, A2[q].y, t2);
            t2 = fmaf(gq.z, A2[q].z, t2); t2 = fmaf(gq.w, A2[q].w, t2);
        }
        const float w0 = fmaf(B0, ue.w, t0);
        const float w1 = fmaf(B1, ue.w, t1);
        const float w2 = fmaf(B2, ue.w, t2);

        // one 16B gather: {phi0,phi1,phi2,pad, vx,vy,vz,pad} bf16
        const uint4 rv = *(const uint4*)(rec + ((size_t)j * FEAT + f) * 8);
        const float p0 = __uint_as_float(rv.x << 16);
        const float p1 = __uint_as_float(rv.x & 0xffff0000u);
        const float p2 = __uint_as_float(rv.y << 16);
        const float vx = __uint_as_float(rv.z << 16);
        const float vy = __uint_as_float(rv.z & 0xffff0000u);
        const float vz = __uint_as_float(rv.w << 16);

        const float i0 = w0 * p0;
        const float i1 = w1 * p1;
        const float i2 = w2 * p2;
        ds += i1;
        dv0 = fmaf(i2, ue.x, fmaf(i0, vx, dv0));
        dv1 = fmaf(i2, ue.y, fmaf(i0, vy, dv1));
        dv2 = fmaf(i2, ue.z, fmaf(i0, vz, dv2));
    }

    ST<F32>(out, (size_t)i * FEAT + f, ds);
    const size_t ob = (size_t)nN * FEAT + ((size_t)i * FEAT + f) * 3;
    ST<F32>(out, ob + 0, dv0);
    ST<F32>(out, ob + 1, dv1);
    ST<F32>(out, ob + 2, dv2);
}

__global__ __launch_bounds__(128, 2) void msg_c_kernel(const float* WdT, const bf16* rec,
        const float* gbuf, const int* src_ids, const float4* u_env, const int* offsets,
        const int* __restrict__ flags, void* out, int nE, int nN) {
    if (flags[0]) msg_c_body<1>(WdT, rec, gbuf, src_ids, u_env, offsets, out, nE, nN);
    else          msg_c_body<0>(WdT, rec, gbuf, src_ids, u_env, offsets, out, nE, nN);
}

// ---------- mode B message (exact R0 baseline fallback) ----------
template<int F32>
__device__ void msg_b_body(const void* __restrict__ v_j, const void* __restrict__ Wd,
        const void* __restrict__ bd, const bf16* __restrict__ phi,
        const float* __restrict__ gbuf, const int* __restrict__ src_ids,
        const float4* __restrict__ u_env, const int* __restrict__ offsets,
        void* __restrict__ out, int nE, int nN) {
    const int i = blockIdx.x;
    const int f = threadIdx.x;

    float wd0[NRBF], wd1[NRBF], wd2[NRBF];
    #pragma unroll
    for (int k = 0; k < NRBF; ++k) {
        wd0[k] = LD<F32>(Wd, (size_t)k * 384 + f);
        wd1[k] = LD<F32>(Wd, (size_t)k * 384 + FEAT + f);
        wd2[k] = LD<F32>(Wd, (size_t)k * 384 + 2 * FEAT + f);
    }
    const float bd0 = LD<F32>(bd, f);
    const float bd1 = LD<F32>(bd, FEAT + f);
    const float bd2 = LD<F32>(bd, 2 * FEAT + f);

    int start = offsets[i];
    int end   = offsets[i + 1];
    if (start < 0) start = 0;
    if (end > nE) end = nE;

    float ds = 0.f, dv0 = 0.f, dv1 = 0.f, dv2 = 0.f;

    for (int p = start; p < end; ++p) {
        const int j = src_ids[p];
        const float4 ue = u_env[p];
        const float* g = gbuf + (size_t)p * NRBF;
        float t0 = 0.f, t1 = 0.f, t2 = 0.f;
        #pragma unroll
        for (int k = 0; k < NRBF; ++k) {
            const float gk = g[k];
            t0 = fmaf(gk, wd0[k], t0);
            t1 = fmaf(gk, wd1[k], t1);
            t2 = fmaf(gk, wd2[k], t2);
        }
        const float w0 = fmaf(bd0, ue.w, t0);
        const float w1 = fmaf(bd1, ue.w, t1);
        const float w2 = fmaf(bd2, ue.w, t2);

        const bf16* ph = phi + (size_t)j * 384;
        const float p0 = b2f(ph[f]);
        const float p1 = b2f(ph[FEAT + f]);
        const float p2 = b2f(ph[2 * FEAT + f]);
        const float vx = LD<F32>(v_j, ((size_t)j * FEAT + f) * 3 + 0);
        const float vy = LD<F32>(v_j, ((size_t)j * FEAT + f) * 3 + 1);
        const float vz = LD<F32>(v_j, ((size_t)j * FEAT + f) * 3 + 2);

        const float i0 = w0 * p0;
        const float i1 = w1 * p1;
        const float i2 = w2 * p2;
        ds += i1;
        dv0 = fmaf(i2, ue.x, fmaf(i0, vx, dv0));
        dv1 = fmaf(i2, ue.y, fmaf(i0, vy, dv1));
        dv2 = fmaf(i2, ue.z, fmaf(i0, vz, dv2));
    }

    ST<F32>(out, (size_t)i * FEAT + f, ds);
    const size_t ob = (size_t)nN * FEAT + ((size_t)i * FEAT + f) * 3;
    ST<F32>(out, ob + 0, dv0);
    ST<F32>(out, ob + 1, dv1);
    ST<F32>(out, ob + 2, dv2);
}

__global__ __launch_bounds__(128) void msg_b_kernel(const void* v_j, const void* Wd,
        const void* bd, const bf16* phi, const float* gbuf, const int* src_ids,
        const float4* u_env, const int* offsets, const int* __restrict__ flags,
        void* out, int nE, int nN) {
    if (flags[0]) msg_b_body<1>(v_j, Wd, bd, phi, gbuf, src_ids, u_env, offsets, out, nE, nN);
    else          msg_b_body<0>(v_j, Wd, bd, phi, gbuf, src_ids, u_env, offsets, out, nE, nN);
}

extern "C" void kernel_launch(void* const* d_in, const int* in_sizes, int n_in,
                              void* d_out, int out_size, void* d_ws, size_t ws_size,
                              hipStream_t stream) {
    const void* s_j  = d_in[0];
    const void* v_j  = d_in[1];
    const void* r_ij = d_in[2];
    const int*  nbrs = (const int*)d_in[3];
    const void* W1   = d_in[4];
    const void* b1   = d_in[5];
    const void* W2   = d_in[6];
    const void* b2   = d_in[7];
    const void* Wd   = d_in[8];
    const void* bd   = d_in[9];

    const int nN = out_size / (4 * FEAT);   // 20000
    const int nE = in_sizes[2] / 3;         // 640000

    char* ws = (char*)d_ws;
    size_t off = 0;
    auto alloc = [&](size_t bytes) -> void* {
        void* p = ws + off;
        off = (off + bytes + 255) & ~(size_t)255;
        return p;
    };
    int*    flags    = (int*)alloc(16);
    int*    counts   = (int*)alloc((size_t)nN * 4);
    int*    offsets  = (int*)alloc(((size_t)nN + 1) * 4);
    int*    cursor   = (int*)alloc((size_t)nN * 4);
    int*    src_ids  = (int*)alloc((size_t)nE * 4);
    float4* u_env    = (float4*)alloc((size_t)nE * 16);
    float*  WdT      = (float*)alloc((size_t)384 * 24 * 4);
    const size_t base = off;

    // mode A layout: pos_of_e | phi | ws_w
    size_t offA = base;
    int*  pos_of_e = (int*)(ws + offA);  offA += ((size_t)nE * 4 + 255) & ~(size_t)255;
    bf16* phiA     = (bf16*)(ws + offA); offA += ((size_t)nN * 384 * 2 + 255) & ~(size_t)255;
    bf16* ws_w     = (bf16*)(ws + offA); offA += (size_t)nE * 384 * 2;
    // mode C layout: gbuf | rec | edge_of_pos
    size_t offC = base;
    float* gbufC = (float*)(ws + offC);  offC += ((size_t)nE * NRBF * 4 + 255) & ~(size_t)255;
    bf16*  rec   = (bf16*)(ws + offC);   offC += ((size_t)nN * FEAT * 8 * 2 + 255) & ~(size_t)255;
    int* edge_of_pos = (int*)(ws + offC); offC += (size_t)nE * 4;
    // mode B layout: gbuf | phi
    size_t offB = base;
    float* gbufB = (float*)(ws + offB);  offB += ((size_t)nE * NRBF * 4 + 255) & ~(size_t)255;
    bf16*  phiB  = (bf16*)(ws + offB);   offB += (size_t)nN * 384 * 2;

    const int modeA = (ws_size >= offA) ? 1 : 0;
    const int modeC = (!modeA && ws_size >= offC) ? 1 : 0;

    init_kernel<<<(nN + 255) / 256, 256, 0, stream>>>(s_j, nbrs, nE, flags, counts, nN);
    hist_kernel<<<(nE + 255) / 256, 256, 0, stream>>>(nbrs, flags, counts, nE, nN);
    scan_kernel<<<1, 1024, 0, stream>>>(counts, offsets, cursor, nN);
    prep_kernel<<<1, 384, 0, stream>>>(Wd, bd, WdT, flags);

    const int psMode = modeA ? 1 : (modeC ? 2 : 0);
    pre_scatter_kernel<<<(nE + 255) / 256, 256, 0, stream>>>(
        r_ij, nbrs, flags, cursor, src_ids, u_env, pos_of_e, gbufC, edge_of_pos,
        nE, nN, psMode);

    if (modeA) {
        gemm_node_kernel<<<(nN + 7) / 8, 384, 0, stream>>>(s_j, W1, b1, W2, b2, phiA, flags, nN, 0);
        pre_ws_kernel<<<(nE + 255) / 256, 256, 0, stream>>>(r_ij, WdT, pos_of_e, ws_w, flags, nE);
        msg_a_kernel<<<nN, 128, 0, stream>>>(ws_w, phiA, v_j, src_ids, u_env, offsets,
                                             flags, d_out, nE, nN);
    } else if (modeC) {
        finalize_kernel<<<(nE + 255) / 256, 256, 0, stream>>>(r_ij, edge_of_pos, u_env,
                                                              gbufC, flags, nE);
        gemm_node_kernel<<<(nN + 7) / 8, 384, 0, stream>>>(s_j, W1, b1, W2, b2, rec, flags, nN, 1);
        pack_v_kernel<<<((nN * FEAT) + 255) / 256, 256, 0, stream>>>(v_j, rec, flags, nN);
        msg_c_kernel<<<nN, 128, 0, stream>>>(WdT, rec, gbufC, src_ids, u_env, offsets,
                                             flags, d_out, nE, nN);
    } else {
        gemm_node_kernel<<<(nN + 7) / 8, 384, 0, stream>>>(s_j, W1, b1, W2, b2, phiB, flags, nN, 0);
        msg_b_kernel<<<nN, 128, 0, stream>>>(v_j, Wd, bd, phiB, gbufC, src_ids, u_env,
                                             offsets, flags, d_out, nE, nN);
    }
}

// Round 7
// 542.709 us; speedup vs baseline: 1.0314x; 1.0314x over previous
//
#include <hip/hip_runtime.h>
#include <hip/hip_bf16.h>
#include <math.h>

typedef __hip_bfloat16 bf16;

#define FEAT 128
#define NRBF 20
#define CUTOFF_F 5.0f
#define KSCALE 0.62831853071795864769f  // pi / 5

__device__ __forceinline__ float b2f(bf16 x) { return __bfloat162float(x); }
__device__ __forceinline__ bf16 f2b(float x) { return __float2bfloat16(x); }

template<int F32>
__device__ __forceinline__ float LD(const void* p, size_t i) {
    if (F32) return ((const float*)p)[i];
    return b2f(((const bf16*)p)[i]);
}
template<int F32>
__device__ __forceinline__ void ST(void* p, size_t i, float v) {
    if (F32) ((float*)p)[i] = v;
    else ((bf16*)p)[i] = f2b(v);
}

__device__ __forceinline__ int get_dst(const int* nb, int e, int is64) {
    return is64 ? nb[4 * e] : nb[2 * e];
}
__device__ __forceinline__ int get_src(const int* nb, int e, int is64) {
    return is64 ? nb[4 * e + 2] : nb[2 * e + 1];
}
__device__ __forceinline__ int clampi(int v, int n) {
    return v < 0 ? 0 : (v >= n ? n - 1 : v);
}

// ---------- init: zero counts + sniff dtypes ----------
__global__ void init_kernel(const void* __restrict__ s_ptr, const int* __restrict__ nbrs32,
                            int nE, int* __restrict__ flags, int* __restrict__ counts, int nN) {
    int t = blockIdx.x * blockDim.x + threadIdx.x;
    if (t < nN) counts[t] = 0;
    if (t == 0) {
        const unsigned* u = (const unsigned*)s_ptr;
        int hits = 0;
        for (int i = 0; i < 64; ++i) {
            unsigned ef = (u[i] >> 7) & 0xFF;
            hits += (ef >= 110 && ef <= 135) ? 1 : 0;
        }
        flags[0] = (hits < 32) ? 1 : 0;   // 1 => f32 inputs
        int lim = 2 * nE; if (lim > 128) lim = 128;
        int allz = 1;
        for (int i = 1; i < lim; i += 2) allz &= (nbrs32[i] == 0);
        flags[1] = allz;                   // 1 => int64 nbrs
    }
}

// ---------- CSR build ----------
__global__ void hist_kernel(const int* __restrict__ nbrs, const int* __restrict__ flags,
                            int* __restrict__ counts, int nE, int nN) {
    int e = blockIdx.x * blockDim.x + threadIdx.x;
    if (e < nE) {
        int d = clampi(get_dst(nbrs, e, flags[1]), nN);
        atomicAdd(&counts[d], 1);
    }
}

__global__ __launch_bounds__(1024) void scan_kernel(const int* __restrict__ counts,
        int* __restrict__ offsets, int* __restrict__ cursor, int nN) {
    __shared__ int part[1024];
    const int t = threadIdx.x;
    const int chunk = (nN + 1023) / 1024;
    const int base = t * chunk;
    int local[32];
    int sum = 0;
    for (int c = 0; c < chunk && c < 32; ++c) {
        int idx = base + c;
        int v = (idx < nN) ? counts[idx] : 0;
        local[c] = v;
        sum += v;
    }
    part[t] = sum;
    __syncthreads();
    for (int off = 1; off < 1024; off <<= 1) {
        int add = (t >= off) ? part[t - off] : 0;
        __syncthreads();
        part[t] += add;
        __syncthreads();
    }
    int run = part[t] - sum;
    for (int c = 0; c < chunk && c < 32; ++c) {
        int idx = base + c;
        if (idx < nN) { offsets[idx] = run; cursor[idx] = run; run += local[c]; }
    }
    if (t == 1023) offsets[nN] = part[1023];
}

// ---------- prep: WdT[c][0..19] = Wd[k][c] (f32), WdT[c][20] = bd[c]; rows padded to 24 ----------
__global__ __launch_bounds__(384) void prep_kernel(const void* __restrict__ Wd,
        const void* __restrict__ bd, float* __restrict__ WdT, const int* __restrict__ flags) {
    const int c = threadIdx.x;
    const int F32 = flags[0];
    if (F32) {
        for (int k = 0; k < NRBF; ++k) WdT[c * 24 + k] = ((const float*)Wd)[k * 384 + c];
        WdT[c * 24 + 20] = ((const float*)bd)[c];
    } else {
        for (int k = 0; k < NRBF; ++k) WdT[c * 24 + k] = b2f(((const bf16*)Wd)[k * 384 + c]);
        WdT[c * 24 + 20] = b2f(((const bf16*)bd)[c]);
    }
    WdT[c * 24 + 21] = 0.f; WdT[c * 24 + 22] = 0.f; WdT[c * 24 + 23] = 0.f;
}

// ---------- scatter + per-position side records (R4 structure) ----------
// MODEA=0: src_ids + u_env + gbuf (trig here)   MODEA=1: src_ids + u_env + pos_of_e
template<int F32, int MODEA>
__device__ void pre_scatter_body(const void* __restrict__ r_ij, const int* __restrict__ nbrs,
        int is64, int* __restrict__ cursor, int* __restrict__ src_ids,
        float4* __restrict__ u_env, int* __restrict__ pos_of_e, float* __restrict__ gbuf,
        int e, int nE, int nN) {
    const int d = clampi(get_dst(nbrs, e, is64), nN);
    const int j = clampi(get_src(nbrs, e, is64), nN);
    int pos = atomicAdd(&cursor[d], 1);
    pos = clampi(pos, nE);
    src_ids[pos] = j;

    const float rx = LD<F32>(r_ij, (size_t)3 * e + 0);
    const float ry = LD<F32>(r_ij, (size_t)3 * e + 1);
    const float rz = LD<F32>(r_ij, (size_t)3 * e + 2);
    const float d2   = rx * rx + ry * ry + rz * rz + 3e-15f;
    const float invd = rsqrtf(d2);
    const float dd   = d2 * invd;
    const float x  = dd * KSCALE;
    const float c1 = F32 ? cosf(x) : __cosf(x);
    const float env = (dd < CUTOFF_F) ? (0.5f * (c1 + 1.0f)) : 0.0f;
    u_env[pos] = make_float4(rx * invd, ry * invd, rz * invd, env);

    if (MODEA) {
        pos_of_e[e] = pos;
    } else {
        const float s1 = F32 ? sinf(x) : __sinf(x);
        const float scale = invd * env;
        const float tc = 2.0f * c1;
        float skm2 = 0.f, skm1 = s1;
        float* g = gbuf + (size_t)pos * NRBF;
        g[0] = s1 * scale;
        #pragma unroll
        for (int k = 1; k < NRBF; ++k) {
            const float sk = fmaf(tc, skm1, -skm2);
            g[k] = sk * scale;
            skm2 = skm1; skm1 = sk;
        }
    }
}

__global__ __launch_bounds__(256) void pre_scatter_kernel(const void* r_ij, const int* nbrs,
        const int* __restrict__ flags, int* cursor, int* src_ids, float4* u_env,
        int* pos_of_e, float* gbuf, int nE, int nN, int modeA) {
    int e = blockIdx.x * blockDim.x + threadIdx.x;
    if (e >= nE) return;
    const int F32 = flags[0], is64 = flags[1];
    if (modeA) {
        if (F32) pre_scatter_body<1,1>(r_ij, nbrs, is64, cursor, src_ids, u_env, pos_of_e, gbuf, e, nE, nN);
        else     pre_scatter_body<0,1>(r_ij, nbrs, is64, cursor, src_ids, u_env, pos_of_e, gbuf, e, nE, nN);
    } else {
        if (F32) pre_scatter_body<1,0>(r_ij, nbrs, is64, cursor, src_ids, u_env, pos_of_e, gbuf, e, nE, nN);
        else     pre_scatter_body<0,0>(r_ij, nbrs, is64, cursor, src_ids, u_env, pos_of_e, gbuf, e, nE, nN);
    }
}

// ---------- fused node MLP: phi = silu(s@W1+b1)@W2 + b2 ----------
// packed=1: write into rec[node][f][8] slots 0..2 (phi0,phi1,phi2)
template<int F32>
__device__ void gemm_body(const void* __restrict__ s_j, const void* __restrict__ W1,
                          const void* __restrict__ b1, const void* __restrict__ W2,
                          const void* __restrict__ b2v, bf16* __restrict__ phi, int nN,
                          int packed) {
    __shared__ float sl[8][FEAT];
    __shared__ float hl[8][FEAT];
    const int t = threadIdx.x;
    const int n0 = blockIdx.x * 8;
    for (int idx = t; idx < 8 * FEAT; idx += 384) {
        int n = idx >> 7, k = idx & 127;
        int row = n0 + n;
        sl[n][k] = (row < nN) ? LD<F32>(s_j, (size_t)row * FEAT + k) : 0.f;
    }
    __syncthreads();
    for (int idx = t; idx < 8 * FEAT; idx += 384) {
        int n = idx >> 7, f = idx & 127;
        float a = 0.f;
        #pragma unroll 4
        for (int k = 0; k < FEAT; ++k) a = fmaf(sl[n][k], LD<F32>(W1, (size_t)k * FEAT + f), a);
        a += LD<F32>(b1, f);
        float sg = F32 ? (1.0f / (1.0f + expf(-a))) : (1.0f / (1.0f + __expf(-a)));
        hl[n][f] = a * sg;
    }
    __syncthreads();
    float acc[8] = {};
    #pragma unroll 4
    for (int k = 0; k < FEAT; ++k) {
        const float w = LD<F32>(W2, (size_t)k * 384 + t);
        #pragma unroll
        for (int n = 0; n < 8; ++n) acc[n] = fmaf(hl[n][k], w, acc[n]);
    }
    const float bb = LD<F32>(b2v, t);
    const int fch  = t & 127;
    const int comp = t >> 7;
    #pragma unroll
    for (int n = 0; n < 8; ++n) {
        int row = n0 + n;
        if (row < nN) {
            if (packed) phi[((size_t)row * FEAT + fch) * 8 + comp] = f2b(acc[n] + bb);
            else        phi[(size_t)row * 384 + t] = f2b(acc[n] + bb);
        }
    }
}

__global__ __launch_bounds__(384) void gemm_node_kernel(const void* s_j, const void* W1,
        const void* b1, const void* W2, const void* b2v, bf16* phi,
        const int* __restrict__ flags, int nN, int packed) {
    if (flags[0]) gemm_body<1>(s_j, W1, b1, W2, b2v, phi, nN, packed);
    else          gemm_body<0>(s_j, W1, b1, W2, b2v, phi, nN, packed);
}

// ---------- mode C: pack v_j (->bf16) into rec slots 4..6 ----------
__global__ __launch_bounds__(256) void pack_v_kernel(const void* __restrict__ v_j,
        bf16* __restrict__ rec, const int* __restrict__ flags, int nN) {
    int t = blockIdx.x * blockDim.x + threadIdx.x;   // t over nN*FEAT
    if (t >= nN * FEAT) return;
    float vx, vy, vz;
    if (flags[0]) {
        const float* v = (const float*)v_j;
        vx = v[(size_t)3 * t + 0];
        vy = v[(size_t)3 * t + 1];
        vz = v[(size_t)3 * t + 2];
    } else {
        const bf16* v = (const bf16*)v_j;
        vx = b2f(v[(size_t)3 * t + 0]);
        vy = b2f(v[(size_t)3 * t + 1]);
        vz = b2f(v[(size_t)3 * t + 2]);
    }
    bf16* d = rec + (size_t)t * 8;
    union { bf16 b[2]; unsigned u; } p01;
    p01.b[0] = f2b(vx); p01.b[1] = f2b(vy);
    *(unsigned*)(d + 4) = p01.u;     // byte offset 8, 4-aligned
    d[6] = f2b(vz);
}

// ---------- mode A: per-edge w_s GEMM ----------
template<int F32>
__device__ void pre_ws_body(const void* __restrict__ r_ij, const float* __restrict__ WdT,
        const int* __restrict__ pos_of_e, bf16* __restrict__ ws_w, int e) {
    const float rx = LD<F32>(r_ij, (size_t)3 * e + 0);
    const float ry = LD<F32>(r_ij, (size_t)3 * e + 1);
    const float rz = LD<F32>(r_ij, (size_t)3 * e + 2);
    const float d2   = rx * rx + ry * ry + rz * rz + 3e-15f;
    const float invd = rsqrtf(d2);
    const float dd   = d2 * invd;
    const float x  = dd * KSCALE;
    const float s1 = F32 ? sinf(x) : __sinf(x);
    const float c1 = F32 ? cosf(x) : __cosf(x);
    const float env = (dd < CUTOFF_F) ? (0.5f * (c1 + 1.0f)) : 0.0f;
    const float scale = invd * env;
    float gk[NRBF];
    const float tc = 2.0f * c1;
    float skm2 = 0.f, skm1 = s1;
    gk[0] = s1 * scale;
    #pragma unroll
    for (int k = 1; k < NRBF; ++k) {
        const float sk = fmaf(tc, skm1, -skm2);
        gk[k] = sk * scale;
        skm2 = skm1; skm1 = sk;
    }
    const int pos = pos_of_e[e];
    bf16* dst = ws_w + (size_t)pos * 384;
    for (int c0 = 0; c0 < 384; c0 += 4) {
        float r[4];
        #pragma unroll
        for (int u = 0; u < 4; ++u) {
            const float* w = WdT + (size_t)(c0 + u) * 24;
            float acc = w[20] * env;
            #pragma unroll
            for (int k = 0; k < NRBF; ++k) acc = fmaf(gk[k], w[k], acc);
            r[u] = acc;
        }
        union { bf16 b[4]; uint2 u2; } pk;
        pk.b[0] = f2b(r[0]); pk.b[1] = f2b(r[1]); pk.b[2] = f2b(r[2]); pk.b[3] = f2b(r[3]);
        *(uint2*)(dst + c0) = pk.u2;
    }
}

__global__ __launch_bounds__(256) void pre_ws_kernel(const void* r_ij,
        const float* __restrict__ WdT, const int* __restrict__ pos_of_e,
        bf16* __restrict__ ws_w, const int* __restrict__ flags, int nE) {
    int e = blockIdx.x * blockDim.x + threadIdx.x;
    if (e >= nE) return;
    if (flags[0]) pre_ws_body<1>(r_ij, WdT, pos_of_e, ws_w, e);
    else          pre_ws_body<0>(r_ij, WdT, pos_of_e, ws_w, e);
}

// ---------- mode A message: pure gather-accumulate ----------
template<int F32>
__device__ void msg_a_body(const bf16* __restrict__ ws_w, const bf16* __restrict__ phi,
        const void* __restrict__ v_j, const int* __restrict__ src_ids,
        const float4* __restrict__ u_env, const int* __restrict__ offsets,
        void* __restrict__ out, int nE, int nN) {
    const int i = blockIdx.x;
    const int f = threadIdx.x;
    int start = offsets[i];
    int end   = offsets[i + 1];
    if (start < 0) start = 0;
    if (end > nE) end = nE;

    float ds = 0.f, dv0 = 0.f, dv1 = 0.f, dv2 = 0.f;

    #pragma unroll 2
    for (int p = start; p < end; ++p) {
        const int j = src_ids[p];
        const float4 ue = u_env[p];
        const bf16* wr = ws_w + (size_t)p * 384;
        const float w0 = b2f(wr[f]);
        const float w1 = b2f(wr[FEAT + f]);
        const float w2 = b2f(wr[2 * FEAT + f]);
        const bf16* ph = phi + (size_t)j * 384;
        const float p0 = b2f(ph[f]);
        const float p1 = b2f(ph[FEAT + f]);
        const float p2 = b2f(ph[2 * FEAT + f]);
        const float vx = LD<F32>(v_j, ((size_t)j * FEAT + f) * 3 + 0);
        const float vy = LD<F32>(v_j, ((size_t)j * FEAT + f) * 3 + 1);
        const float vz = LD<F32>(v_j, ((size_t)j * FEAT + f) * 3 + 2);
        const float i0 = w0 * p0;
        const float i1 = w1 * p1;
        const float i2 = w2 * p2;
        ds += i1;
        dv0 = fmaf(i2, ue.x, fmaf(i0, vx, dv0));
        dv1 = fmaf(i2, ue.y, fmaf(i0, vy, dv1));
        dv2 = fmaf(i2, ue.z, fmaf(i0, vz, dv2));
    }

    ST<F32>(out, (size_t)i * FEAT + f, ds);
    const size_t ob = (size_t)nN * FEAT + ((size_t)i * FEAT + f) * 3;
    ST<F32>(out, ob + 0, dv0);
    ST<F32>(out, ob + 1, dv1);
    ST<F32>(out, ob + 2, dv2);
}

__global__ __launch_bounds__(128) void msg_a_kernel(const bf16* ws_w, const bf16* phi,
        const void* v_j, const int* src_ids, const float4* u_env, const int* offsets,
        const int* __restrict__ flags, void* out, int nE, int nN) {
    if (flags[0]) msg_a_body<1>(ws_w, phi, v_j, src_ids, u_env, offsets, out, nE, nN);
    else          msg_a_body<0>(ws_w, phi, v_j, src_ids, u_env, offsets, out, nE, nN);
}

// ---------- mode C message: weights PINNED in VGPRs (asm) + cap 256 ----------
// R7: R1 proved the pin forces liveness (spilled at cap 64); R6 proved cap 256
// alone doesn't persuade the allocator (VGPR stayed 48). Pin + cap 256:
// 63 floats live across the loop, ~100-130 VGPR, still 4 waves/EU.
template<int F32>
__device__ void msg_c_body(const float* __restrict__ WdT, const bf16* __restrict__ rec,
        const float* __restrict__ gbuf, const int* __restrict__ src_ids,
        const float4* __restrict__ u_env, const int* __restrict__ offsets,
        void* __restrict__ out, int nE, int nN) {
    const int i = blockIdx.x;
    const int f = threadIdx.x;
    int start = offsets[i];
    int end   = offsets[i + 1];
    if (start < 0) start = 0;
    if (end > nE) end = nE;

    float w0[21], w1[21], w2[21];
    {
        const float4* q0 = (const float4*)(WdT + (size_t)f * 24);
        const float4* q1 = (const float4*)(WdT + (size_t)(f + FEAT) * 24);
        const float4* q2 = (const float4*)(WdT + (size_t)(f + 2 * FEAT) * 24);
        #pragma unroll
        for (int q = 0; q < 5; ++q) {
            const float4 a = q0[q], b = q1[q], c = q2[q];
            w0[4*q+0] = a.x; w0[4*q+1] = a.y; w0[4*q+2] = a.z; w0[4*q+3] = a.w;
            w1[4*q+0] = b.x; w1[4*q+1] = b.y; w1[4*q+2] = b.z; w1[4*q+3] = b.w;
            w2[4*q+0] = c.x; w2[4*q+1] = c.y; w2[4*q+2] = c.z; w2[4*q+3] = c.w;
        }
        w0[20] = WdT[(size_t)f * 24 + 20];
        w1[20] = WdT[(size_t)(f + FEAT) * 24 + 20];
        w2[20] = WdT[(size_t)(f + 2 * FEAT) * 24 + 20];
    }
    // Force the 63 weights live in VGPRs: opaque to the rematerializer.
    #pragma unroll
    for (int k = 0; k < 21; ++k)
        asm volatile("" : "+v"(w0[k]), "+v"(w1[k]), "+v"(w2[k]));

    float ds = 0.f, dv0 = 0.f, dv1 = 0.f, dv2 = 0.f;

    for (int p = start; p < end; ++p) {
        const int j = src_ids[p];
        const float4 ue = u_env[p];
        const float4* g4 = (const float4*)(gbuf + (size_t)p * NRBF);
        float4 G0 = g4[0], G1 = g4[1], G2 = g4[2], G3 = g4[3], G4 = g4[4];
        // one 16B gather: {phi0,phi1,phi2,pad, vx,vy,vz,pad} bf16
        const uint4 rv = *(const uint4*)(rec + ((size_t)j * FEAT + f) * 8);

        float t0, t1, t2;
        t0 = fmaf(G0.x, w0[0], 0.f); t1 = fmaf(G0.x, w1[0], 0.f); t2 = fmaf(G0.x, w2[0], 0.f);
        t0 = fmaf(G0.y, w0[1], t0);  t1 = fmaf(G0.y, w1[1], t1);  t2 = fmaf(G0.y, w2[1], t2);
        t0 = fmaf(G0.z, w0[2], t0);  t1 = fmaf(G0.z, w1[2], t1);  t2 = fmaf(G0.z, w2[2], t2);
        t0 = fmaf(G0.w, w0[3], t0);  t1 = fmaf(G0.w, w1[3], t1);  t2 = fmaf(G0.w, w2[3], t2);
        t0 = fmaf(G1.x, w0[4], t0);  t1 = fmaf(G1.x, w1[4], t1);  t2 = fmaf(G1.x, w2[4], t2);
        t0 = fmaf(G1.y, w0[5], t0);  t1 = fmaf(G1.y, w1[5], t1);  t2 = fmaf(G1.y, w2[5], t2);
        t0 = fmaf(G1.z, w0[6], t0);  t1 = fmaf(G1.z, w1[6], t1);  t2 = fmaf(G1.z, w2[6], t2);
        t0 = fmaf(G1.w, w0[7], t0);  t1 = fmaf(G1.w, w1[7], t1);  t2 = fmaf(G1.w, w2[7], t2);
        t0 = fmaf(G2.x, w0[8], t0);  t1 = fmaf(G2.x, w1[8], t1);  t2 = fmaf(G2.x, w2[8], t2);
        t0 = fmaf(G2.y, w0[9], t0);  t1 = fmaf(G2.y, w1[9], t1);  t2 = fmaf(G2.y, w2[9], t2);
        t0 = fmaf(G2.z, w0[10], t0); t1 = fmaf(G2.z, w1[10], t1); t2 = fmaf(G2.z, w2[10], t2);
        t0 = fmaf(G2.w, w0[11], t0); t1 = fmaf(G2.w, w1[11], t1); t2 = fmaf(G2.w, w2[11], t2);
        t0 = fmaf(G3.x, w0[12], t0); t1 = fmaf(G3.x, w1[12], t1); t2 = fmaf(G3.x, w2[12], t2);
        t0 = fmaf(G3.y, w0[13], t0); t1 = fmaf(G3.y, w1[13], t1); t2 = fmaf(G3.y, w2[13], t2);
        t0 = fmaf(G3.z, w0[14], t0); t1 = fmaf(G3.z, w1[14], t1); t2 = fmaf(G3.z, w2[14], t2);
        t0 = fmaf(G3.w, w0[15], t0); t1 = fmaf(G3.w, w1[15], t1); t2 = fmaf(G3.w, w2[15], t2);
        t0 = fmaf(G4.x, w0[16], t0); t1 = fmaf(G4.x, w1[16], t1); t2 = fmaf(G4.x, w2[16], t2);
        t0 = fmaf(G4.y, w0[17], t0); t1 = fmaf(G4.y, w1[17], t1); t2 = fmaf(G4.y, w2[17], t2);
        t0 = fmaf(G4.z, w0[18], t0); t1 = fmaf(G4.z, w1[18], t1); t2 = fmaf(G4.z, w2[18], t2);
        t0 = fmaf(G4.w, w0[19], t0); t1 = fmaf(G4.w, w1[19], t1); t2 = fmaf(G4.w, w2[19], t2);

        const float ww0 = fmaf(w0[20], ue.w, t0);
        const float ww1 = fmaf(w1[20], ue.w, t1);
        const float ww2 = fmaf(w2[20], ue.w, t2);

        const float p0 = __uint_as_float(rv.x << 16);
        const float p1 = __uint_as_float(rv.x & 0xffff0000u);
        const float p2 = __uint_as_float(rv.y << 16);
        const float vx = __uint_as_float(rv.z << 16);
        const float vy = __uint_as_float(rv.z & 0xffff0000u);
        const float vz = __uint_as_float(rv.w << 16);

        const float i0 = ww0 * p0;
        const float i1 = ww1 * p1;
        const float i2 = ww2 * p2;
        ds += i1;
        dv0 = fmaf(i2, ue.x, fmaf(i0, vx, dv0));
        dv1 = fmaf(i2, ue.y, fmaf(i0, vy, dv1));
        dv2 = fmaf(i2, ue.z, fmaf(i0, vz, dv2));
    }

    ST<F32>(out, (size_t)i * FEAT + f, ds);
    const size_t ob = (size_t)nN * FEAT + ((size_t)i * FEAT + f) * 3;
    ST<F32>(out, ob + 0, dv0);
    ST<F32>(out, ob + 1, dv1);
    ST<F32>(out, ob + 2, dv2);
}

__global__ __launch_bounds__(128, 2) void msg_c_kernel(const float* WdT, const bf16* rec,
        const float* gbuf, const int* src_ids, const float4* u_env, const int* offsets,
        const int* __restrict__ flags, void* out, int nE, int nN) {
    if (flags[0]) msg_c_body<1>(WdT, rec, gbuf, src_ids, u_env, offsets, out, nE, nN);
    else          msg_c_body<0>(WdT, rec, gbuf, src_ids, u_env, offsets, out, nE, nN);
}

// ---------- mode B message (exact R0 baseline fallback) ----------
template<int F32>
__device__ void msg_b_body(const void* __restrict__ v_j, const void* __restrict__ Wd,
        const void* __restrict__ bd, const bf16* __restrict__ phi,
        const float* __restrict__ gbuf, const int* __restrict__ src_ids,
        const float4* __restrict__ u_env, const int* __restrict__ offsets,
        void* __restrict__ out, int nE, int nN) {
    const int i = blockIdx.x;
    const int f = threadIdx.x;

    float wd0[NRBF], wd1[NRBF], wd2[NRBF];
    #pragma unroll
    for (int k = 0; k < NRBF; ++k) {
        wd0[k] = LD<F32>(Wd, (size_t)k * 384 + f);
        wd1[k] = LD<F32>(Wd, (size_t)k * 384 + FEAT + f);
        wd2[k] = LD<F32>(Wd, (size_t)k * 384 + 2 * FEAT + f);
    }
    const float bd0 = LD<F32>(bd, f);
    const float bd1 = LD<F32>(bd, FEAT + f);
    const float bd2 = LD<F32>(bd, 2 * FEAT + f);

    int start = offsets[i];
    int end   = offsets[i + 1];
    if (start < 0) start = 0;
    if (end > nE) end = nE;

    float ds = 0.f, dv0 = 0.f, dv1 = 0.f, dv2 = 0.f;

    for (int p = start; p < end; ++p) {
        const int j = src_ids[p];
        const float4 ue = u_env[p];
        const float* g = gbuf + (size_t)p * NRBF;
        float t0 = 0.f, t1 = 0.f, t2 = 0.f;
        #pragma unroll
        for (int k = 0; k < NRBF; ++k) {
            const float gk = g[k];
            t0 = fmaf(gk, wd0[k], t0);
            t1 = fmaf(gk, wd1[k], t1);
            t2 = fmaf(gk, wd2[k], t2);
        }
        const float w0 = fmaf(bd0, ue.w, t0);
        const float w1 = fmaf(bd1, ue.w, t1);
        const float w2 = fmaf(bd2, ue.w, t2);

        const bf16* ph = phi + (size_t)j * 384;
        const float p0 = b2f(ph[f]);
        const float p1 = b2f(ph[FEAT + f]);
        const float p2 = b2f(ph[2 * FEAT + f]);
        const float vx = LD<F32>(v_j, ((size_t)j * FEAT + f) * 3 + 0);
        const float vy = LD<F32>(v_j, ((size_t)j * FEAT + f) * 3 + 1);
        const float vz = LD<F32>(v_j, ((size_t)j * FEAT + f) * 3 + 2);

        const float i0 = w0 * p0;
        const float i1 = w1 * p1;
        const float i2 = w2 * p2;
        ds += i1;
        dv0 = fmaf(i2, ue.x, fmaf(i0, vx, dv0));
        dv1 = fmaf(i2, ue.y, fmaf(i0, vy, dv1));
        dv2 = fmaf(i2, ue.z, fmaf(i0, vz, dv2));
    }

    ST<F32>(out, (size_t)i * FEAT + f, ds);
    const size_t ob = (size_t)nN * FEAT + ((size_t)i * FEAT + f) * 3;
    ST<F32>(out, ob + 0, dv0);
    ST<F32>(out, ob + 1, dv1);
    ST<F32>(out, ob + 2, dv2);
}

__global__ __launch_bounds__(128) void msg_b_kernel(const void* v_j, const void* Wd,
        const void* bd, const bf16* phi, const float* gbuf, const int* src_ids,
        const float4* u_env, const int* offsets, const int* __restrict__ flags,
        void* out, int nE, int nN) {
    if (flags[0]) msg_b_body<1>(v_j, Wd, bd, phi, gbuf, src_ids, u_env, offsets, out, nE, nN);
    else          msg_b_body<0>(v_j, Wd, bd, phi, gbuf, src_ids, u_env, offsets, out, nE, nN);
}

extern "C" void kernel_launch(void* const* d_in, const int* in_sizes, int n_in,
                              void* d_out, int out_size, void* d_ws, size_t ws_size,
                              hipStream_t stream) {
    const void* s_j  = d_in[0];
    const void* v_j  = d_in[1];
    const void* r_ij = d_in[2];
    const int*  nbrs = (const int*)d_in[3];
    const void* W1   = d_in[4];
    const void* b1   = d_in[5];
    const void* W2   = d_in[6];
    const void* b2   = d_in[7];
    const void* Wd   = d_in[8];
    const void* bd   = d_in[9];

    const int nN = out_size / (4 * FEAT);   // 20000
    const int nE = in_sizes[2] / 3;         // 640000

    char* ws = (char*)d_ws;
    size_t off = 0;
    auto alloc = [&](size_t bytes) -> void* {
        void* p = ws + off;
        off = (off + bytes + 255) & ~(size_t)255;
        return p;
    };
    int*    flags    = (int*)alloc(16);
    int*    counts   = (int*)alloc((size_t)nN * 4);
    int*    offsets  = (int*)alloc(((size_t)nN + 1) * 4);
    int*    cursor   = (int*)alloc((size_t)nN * 4);
    int*    src_ids  = (int*)alloc((size_t)nE * 4);
    float4* u_env    = (float4*)alloc((size_t)nE * 16);
    float*  WdT      = (float*)alloc((size_t)384 * 24 * 4);
    const size_t base = off;

    // mode A layout: pos_of_e | phi | ws_w
    size_t offA = base;
    int*  pos_of_e = (int*)(ws + offA);  offA += ((size_t)nE * 4 + 255) & ~(size_t)255;
    bf16* phiA     = (bf16*)(ws + offA); offA += ((size_t)nN * 384 * 2 + 255) & ~(size_t)255;
    bf16* ws_w     = (bf16*)(ws + offA); offA += (size_t)nE * 384 * 2;
    // mode C layout: gbuf | rec (packed phi+v, 16B per (node,f))
    size_t offC = base;
    float* gbufC = (float*)(ws + offC);  offC += ((size_t)nE * NRBF * 4 + 255) & ~(size_t)255;
    bf16*  rec   = (bf16*)(ws + offC);   offC += (size_t)nN * FEAT * 8 * 2;
    // mode B layout: gbuf | phi
    size_t offB = base;
    float* gbufB = (float*)(ws + offB);  offB += ((size_t)nE * NRBF * 4 + 255) & ~(size_t)255;
    bf16*  phiB  = (bf16*)(ws + offB);   offB += (size_t)nN * 384 * 2;

    const int modeA = (ws_size >= offA) ? 1 : 0;
    const int modeC = (!modeA && ws_size >= offC) ? 1 : 0;

    init_kernel<<<(nN + 255) / 256, 256, 0, stream>>>(s_j, nbrs, nE, flags, counts, nN);
    hist_kernel<<<(nE + 255) / 256, 256, 0, stream>>>(nbrs, flags, counts, nE, nN);
    scan_kernel<<<1, 1024, 0, stream>>>(counts, offsets, cursor, nN);
    prep_kernel<<<1, 384, 0, stream>>>(Wd, bd, WdT, flags);

    pre_scatter_kernel<<<(nE + 255) / 256, 256, 0, stream>>>(
        r_ij, nbrs, flags, cursor, src_ids, u_env, pos_of_e, gbufC, nE, nN, modeA);

    if (modeA) {
        gemm_node_kernel<<<(nN + 7) / 8, 384, 0, stream>>>(s_j, W1, b1, W2, b2, phiA, flags, nN, 0);
        pre_ws_kernel<<<(nE + 255) / 256, 256, 0, stream>>>(r_ij, WdT, pos_of_e, ws_w, flags, nE);
        msg_a_kernel<<<nN, 128, 0, stream>>>(ws_w, phiA, v_j, src_ids, u_env, offsets,
                                             flags, d_out, nE, nN);
    } else if (modeC) {
        gemm_node_kernel<<<(nN + 7) / 8, 384, 0, stream>>>(s_j, W1, b1, W2, b2, rec, flags, nN, 1);
        pack_v_kernel<<<((nN * FEAT) + 255) / 256, 256, 0, stream>>>(v_j, rec, flags, nN);
        msg_c_kernel<<<nN, 128, 0, stream>>>(WdT, rec, gbufC, src_ids, u_env, offsets,
                                             flags, d_out, nE, nN);
    } else {
        gemm_node_kernel<<<(nN + 7) / 8, 384, 0, stream>>>(s_j, W1, b1, W2, b2, phiB, flags, nN, 0);
        msg_b_kernel<<<nN, 128, 0, stream>>>(v_j, Wd, bd, phiB, gbufC, src_ids, u_env,
                                             offsets, flags, d_out, nE, nN);
    }
}

// Round 8
// 538.689 us; speedup vs baseline: 1.0391x; 1.0075x over previous
//
#include <hip/hip_runtime.h>
#include <hip/hip_bf16.h>
#include <math.h>

typedef __hip_bfloat16 bf16;

#define FEAT 128
#define NRBF 20
#define CUTOFF_F 5.0f
#define KSCALE 0.62831853071795864769f  // pi / 5
#define NB 4096
#define INV_H 819.0f                    // (NB-1)/CUTOFF
#define H_STEP 0.001221001221001221f    // CUTOFF/(NB-1)

__device__ __forceinline__ float b2f(bf16 x) { return __bfloat162float(x); }
__device__ __forceinline__ bf16 f2b(float x) { return __float2bfloat16(x); }
__device__ __forceinline__ float us2f(unsigned short u) {
    return __uint_as_float(((unsigned)u) << 16);
}

template<int F32>
__device__ __forceinline__ float LD(const void* p, size_t i) {
    if (F32) return ((const float*)p)[i];
    return b2f(((const bf16*)p)[i]);
}
template<int F32>
__device__ __forceinline__ void ST(void* p, size_t i, float v) {
    if (F32) ((float*)p)[i] = v;
    else ((bf16*)p)[i] = f2b(v);
}

__device__ __forceinline__ int get_dst(const int* nb, int e, int is64) {
    return is64 ? nb[4 * e] : nb[2 * e];
}
__device__ __forceinline__ int get_src(const int* nb, int e, int is64) {
    return is64 ? nb[4 * e + 2] : nb[2 * e + 1];
}
__device__ __forceinline__ int clampi(int v, int n) {
    return v < 0 ? 0 : (v >= n ? n - 1 : v);
}

// ---------- init: zero counts + sniff dtypes ----------
__global__ void init_kernel(const void* __restrict__ s_ptr, const int* __restrict__ nbrs32,
                            int nE, int* __restrict__ flags, int* __restrict__ counts, int nN) {
    int t = blockIdx.x * blockDim.x + threadIdx.x;
    if (t < nN) counts[t] = 0;
    if (t == 0) {
        const unsigned* u = (const unsigned*)s_ptr;
        int hits = 0;
        for (int i = 0; i < 64; ++i) {
            unsigned ef = (u[i] >> 7) & 0xFF;
            hits += (ef >= 110 && ef <= 135) ? 1 : 0;
        }
        flags[0] = (hits < 32) ? 1 : 0;   // 1 => f32 inputs
        int lim = 2 * nE; if (lim > 128) lim = 128;
        int allz = 1;
        for (int i = 1; i < lim; i += 2) allz &= (nbrs32[i] == 0);
        flags[1] = allz;                   // 1 => int64 nbrs
    }
}

// ---------- CSR build ----------
__global__ void hist_kernel(const int* __restrict__ nbrs, const int* __restrict__ flags,
                            int* __restrict__ counts, int nE, int nN) {
    int e = blockIdx.x * blockDim.x + threadIdx.x;
    if (e < nE) {
        int d = clampi(get_dst(nbrs, e, flags[1]), nN);
        atomicAdd(&counts[d], 1);
    }
}

__global__ __launch_bounds__(1024) void scan_kernel(const int* __restrict__ counts,
        int* __restrict__ offsets, int* __restrict__ cursor, int nN) {
    __shared__ int part[1024];
    const int t = threadIdx.x;
    const int chunk = (nN + 1023) / 1024;
    const int base = t * chunk;
    int local[32];
    int sum = 0;
    for (int c = 0; c < chunk && c < 32; ++c) {
        int idx = base + c;
        int v = (idx < nN) ? counts[idx] : 0;
        local[c] = v;
        sum += v;
    }
    part[t] = sum;
    __syncthreads();
    for (int off = 1; off < 1024; off <<= 1) {
        int add = (t >= off) ? part[t - off] : 0;
        __syncthreads();
        part[t] += add;
        __syncthreads();
    }
    int run = part[t] - sum;
    for (int c = 0; c < chunk && c < 32; ++c) {
        int idx = base + c;
        if (idx < nN) { offsets[idx] = run; cursor[idx] = run; run += local[c]; }
    }
    if (t == 1023) offsets[nN] = part[1023];
}

// ---------- prep: WdT[c][0..19] = Wd[k][c] (f32), WdT[c][20] = bd[c]; rows padded to 24 ----------
__global__ __launch_bounds__(384) void prep_kernel(const void* __restrict__ Wd,
        const void* __restrict__ bd, float* __restrict__ WdT, const int* __restrict__ flags) {
    const int c = threadIdx.x;
    const int F32 = flags[0];
    if (F32) {
        for (int k = 0; k < NRBF; ++k) WdT[c * 24 + k] = ((const float*)Wd)[k * 384 + c];
        WdT[c * 24 + 20] = ((const float*)bd)[c];
    } else {
        for (int k = 0; k < NRBF; ++k) WdT[c * 24 + k] = b2f(((const bf16*)Wd)[k * 384 + c]);
        WdT[c * 24 + 20] = b2f(((const bf16*)bd)[c]);
    }
    WdT[c * 24 + 21] = 0.f; WdT[c * 24 + 22] = 0.f; WdT[c * 24 + 23] = 0.f;
}

// ---------- mode C: w_s lookup table over distance ----------
// tab[b][c] = (rbf(d_b)@Wd + bd)[c] * env(d_b),  d_b = b*H_STEP, bf16
__global__ __launch_bounds__(384) void build_table_kernel(const float* __restrict__ WdT,
        bf16* __restrict__ tab) {
    const int b = blockIdx.x;
    const int c = threadIdx.x;
    const float d = fmaxf(b * H_STEP, 1e-7f);
    const float x = d * KSCALE;
    const float s1 = sinf(x);
    const float c1 = cosf(x);
    const float env = (d < CUTOFF_F) ? (0.5f * (c1 + 1.0f)) : 0.0f;
    const float invd = 1.0f / d;
    float g[NRBF];
    const float tc = 2.0f * c1;
    float skm2 = 0.f, skm1 = s1;
    g[0] = s1 * invd;
    #pragma unroll
    for (int k = 1; k < NRBF; ++k) {
        const float sk = fmaf(tc, skm1, -skm2);
        g[k] = sk * invd;
        skm2 = skm1; skm1 = sk;
    }
    const float* w = WdT + (size_t)c * 24;
    float acc = w[20];                      // bd
    #pragma unroll
    for (int k = 0; k < NRBF; ++k) acc = fmaf(g[k], w[k], acc);
    tab[(size_t)b * 384 + c] = f2b(acc * env);
}

// ---------- scatter + per-position side records ----------
// MODE 0 (B): src_ids + u_env{unit,env} + gbuf (trig here)
// MODE 1 (A): src_ids + u_env{unit,env} + pos_of_e (trig here)
// MODE 2 (C): src_ids + u_env{unit,d}  (NO trig, NO gbuf -> 20B/edge scattered)
template<int F32, int MODE>
__device__ void pre_scatter_body(const void* __restrict__ r_ij, const int* __restrict__ nbrs,
        int is64, int* __restrict__ cursor, int* __restrict__ src_ids,
        float4* __restrict__ u_env, int* __restrict__ pos_of_e, float* __restrict__ gbuf,
        int e, int nE, int nN) {
    const int d = clampi(get_dst(nbrs, e, is64), nN);
    const int j = clampi(get_src(nbrs, e, is64), nN);
    int pos = atomicAdd(&cursor[d], 1);
    pos = clampi(pos, nE);
    src_ids[pos] = j;

    const float rx = LD<F32>(r_ij, (size_t)3 * e + 0);
    const float ry = LD<F32>(r_ij, (size_t)3 * e + 1);
    const float rz = LD<F32>(r_ij, (size_t)3 * e + 2);
    const float d2   = rx * rx + ry * ry + rz * rz + 3e-15f;
    const float invd = rsqrtf(d2);
    const float dd   = d2 * invd;

    if (MODE == 2) {
        u_env[pos] = make_float4(rx * invd, ry * invd, rz * invd, dd);
        return;
    }

    const float x  = dd * KSCALE;
    const float c1 = F32 ? cosf(x) : __cosf(x);
    const float env = (dd < CUTOFF_F) ? (0.5f * (c1 + 1.0f)) : 0.0f;
    u_env[pos] = make_float4(rx * invd, ry * invd, rz * invd, env);

    if (MODE == 1) {
        pos_of_e[e] = pos;
    } else {
        const float s1 = F32 ? sinf(x) : __sinf(x);
        const float scale = invd * env;
        const float tc = 2.0f * c1;
        float skm2 = 0.f, skm1 = s1;
        float* g = gbuf + (size_t)pos * NRBF;
        g[0] = s1 * scale;
        #pragma unroll
        for (int k = 1; k < NRBF; ++k) {
            const float sk = fmaf(tc, skm1, -skm2);
            g[k] = sk * scale;
            skm2 = skm1; skm1 = sk;
        }
    }
}

__global__ __launch_bounds__(256) void pre_scatter_kernel(const void* r_ij, const int* nbrs,
        const int* __restrict__ flags, int* cursor, int* src_ids, float4* u_env,
        int* pos_of_e, float* gbuf, int nE, int nN, int mode) {
    int e = blockIdx.x * blockDim.x + threadIdx.x;
    if (e >= nE) return;
    const int F32 = flags[0], is64 = flags[1];
    if (mode == 2) {
        if (F32) pre_scatter_body<1,2>(r_ij, nbrs, is64, cursor, src_ids, u_env, pos_of_e, gbuf, e, nE, nN);
        else     pre_scatter_body<0,2>(r_ij, nbrs, is64, cursor, src_ids, u_env, pos_of_e, gbuf, e, nE, nN);
    } else if (mode == 1) {
        if (F32) pre_scatter_body<1,1>(r_ij, nbrs, is64, cursor, src_ids, u_env, pos_of_e, gbuf, e, nE, nN);
        else     pre_scatter_body<0,1>(r_ij, nbrs, is64, cursor, src_ids, u_env, pos_of_e, gbuf, e, nE, nN);
    } else {
        if (F32) pre_scatter_body<1,0>(r_ij, nbrs, is64, cursor, src_ids, u_env, pos_of_e, gbuf, e, nE, nN);
        else     pre_scatter_body<0,0>(r_ij, nbrs, is64, cursor, src_ids, u_env, pos_of_e, gbuf, e, nE, nN);
    }
}

// ---------- fused node MLP: phi = silu(s@W1+b1)@W2 + b2 ----------
// packed=1: write into rec[node][f][8] slots 0..2 (phi0,phi1,phi2)
template<int F32>
__device__ void gemm_body(const void* __restrict__ s_j, const void* __restrict__ W1,
                          const void* __restrict__ b1, const void* __restrict__ W2,
                          const void* __restrict__ b2v, bf16* __restrict__ phi, int nN,
                          int packed) {
    __shared__ float sl[8][FEAT];
    __shared__ float hl[8][FEAT];
    const int t = threadIdx.x;
    const int n0 = blockIdx.x * 8;
    for (int idx = t; idx < 8 * FEAT; idx += 384) {
        int n = idx >> 7, k = idx & 127;
        int row = n0 + n;
        sl[n][k] = (row < nN) ? LD<F32>(s_j, (size_t)row * FEAT + k) : 0.f;
    }
    __syncthreads();
    for (int idx = t; idx < 8 * FEAT; idx += 384) {
        int n = idx >> 7, f = idx & 127;
        float a = 0.f;
        #pragma unroll 4
        for (int k = 0; k < FEAT; ++k) a = fmaf(sl[n][k], LD<F32>(W1, (size_t)k * FEAT + f), a);
        a += LD<F32>(b1, f);
        float sg = F32 ? (1.0f / (1.0f + expf(-a))) : (1.0f / (1.0f + __expf(-a)));
        hl[n][f] = a * sg;
    }
    __syncthreads();
    float acc[8] = {};
    #pragma unroll 4
    for (int k = 0; k < FEAT; ++k) {
        const float w = LD<F32>(W2, (size_t)k * 384 + t);
        #pragma unroll
        for (int n = 0; n < 8; ++n) acc[n] = fmaf(hl[n][k], w, acc[n]);
    }
    const float bb = LD<F32>(b2v, t);
    const int fch  = t & 127;
    const int comp = t >> 7;
    #pragma unroll
    for (int n = 0; n < 8; ++n) {
        int row = n0 + n;
        if (row < nN) {
            if (packed) phi[((size_t)row * FEAT + fch) * 8 + comp] = f2b(acc[n] + bb);
            else        phi[(size_t)row * 384 + t] = f2b(acc[n] + bb);
        }
    }
}

__global__ __launch_bounds__(384) void gemm_node_kernel(const void* s_j, const void* W1,
        const void* b1, const void* W2, const void* b2v, bf16* phi,
        const int* __restrict__ flags, int nN, int packed) {
    if (flags[0]) gemm_body<1>(s_j, W1, b1, W2, b2v, phi, nN, packed);
    else          gemm_body<0>(s_j, W1, b1, W2, b2v, phi, nN, packed);
}

// ---------- mode C: pack v_j (->bf16) into rec slots 4..6 ----------
__global__ __launch_bounds__(256) void pack_v_kernel(const void* __restrict__ v_j,
        bf16* __restrict__ rec, const int* __restrict__ flags, int nN) {
    int t = blockIdx.x * blockDim.x + threadIdx.x;   // t over nN*FEAT
    if (t >= nN * FEAT) return;
    float vx, vy, vz;
    if (flags[0]) {
        const float* v = (const float*)v_j;
        vx = v[(size_t)3 * t + 0];
        vy = v[(size_t)3 * t + 1];
        vz = v[(size_t)3 * t + 2];
    } else {
        const bf16* v = (const bf16*)v_j;
        vx = b2f(v[(size_t)3 * t + 0]);
        vy = b2f(v[(size_t)3 * t + 1]);
        vz = b2f(v[(size_t)3 * t + 2]);
    }
    bf16* d = rec + (size_t)t * 8;
    union { bf16 b[2]; unsigned u; } p01;
    p01.b[0] = f2b(vx); p01.b[1] = f2b(vy);
    *(unsigned*)(d + 4) = p01.u;     // byte offset 8, 4-aligned
    d[6] = f2b(vz);
}

// ---------- mode A: per-edge w_s GEMM ----------
template<int F32>
__device__ void pre_ws_body(const void* __restrict__ r_ij, const float* __restrict__ WdT,
        const int* __restrict__ pos_of_e, bf16* __restrict__ ws_w, int e) {
    const float rx = LD<F32>(r_ij, (size_t)3 * e + 0);
    const float ry = LD<F32>(r_ij, (size_t)3 * e + 1);
    const float rz = LD<F32>(r_ij, (size_t)3 * e + 2);
    const float d2   = rx * rx + ry * ry + rz * rz + 3e-15f;
    const float invd = rsqrtf(d2);
    const float dd   = d2 * invd;
    const float x  = dd * KSCALE;
    const float s1 = F32 ? sinf(x) : __sinf(x);
    const float c1 = F32 ? cosf(x) : __cosf(x);
    const float env = (dd < CUTOFF_F) ? (0.5f * (c1 + 1.0f)) : 0.0f;
    const float scale = invd * env;
    float gk[NRBF];
    const float tc = 2.0f * c1;
    float skm2 = 0.f, skm1 = s1;
    gk[0] = s1 * scale;
    #pragma unroll
    for (int k = 1; k < NRBF; ++k) {
        const float sk = fmaf(tc, skm1, -skm2);
        gk[k] = sk * scale;
        skm2 = skm1; skm1 = sk;
    }
    const int pos = pos_of_e[e];
    bf16* dst = ws_w + (size_t)pos * 384;
    for (int c0 = 0; c0 < 384; c0 += 4) {
        float r[4];
        #pragma unroll
        for (int u = 0; u < 4; ++u) {
            const float* w = WdT + (size_t)(c0 + u) * 24;
            float acc = w[20] * env;
            #pragma unroll
            for (int k = 0; k < NRBF; ++k) acc = fmaf(gk[k], w[k], acc);
            r[u] = acc;
        }
        union { bf16 b[4]; uint2 u2; } pk;
        pk.b[0] = f2b(r[0]); pk.b[1] = f2b(r[1]); pk.b[2] = f2b(r[2]); pk.b[3] = f2b(r[3]);
        *(uint2*)(dst + c0) = pk.u2;
    }
}

__global__ __launch_bounds__(256) void pre_ws_kernel(const void* r_ij,
        const float* __restrict__ WdT, const int* __restrict__ pos_of_e,
        bf16* __restrict__ ws_w, const int* __restrict__ flags, int nE) {
    int e = blockIdx.x * blockDim.x + threadIdx.x;
    if (e >= nE) return;
    if (flags[0]) pre_ws_body<1>(r_ij, WdT, pos_of_e, ws_w, e);
    else          pre_ws_body<0>(r_ij, WdT, pos_of_e, ws_w, e);
}

// ---------- mode A message: pure gather-accumulate ----------
template<int F32>
__device__ void msg_a_body(const bf16* __restrict__ ws_w, const bf16* __restrict__ phi,
        const void* __restrict__ v_j, const int* __restrict__ src_ids,
        const float4* __restrict__ u_env, const int* __restrict__ offsets,
        void* __restrict__ out, int nE, int nN) {
    const int i = blockIdx.x;
    const int f = threadIdx.x;
    int start = offsets[i];
    int end   = offsets[i + 1];
    if (start < 0) start = 0;
    if (end > nE) end = nE;

    float ds = 0.f, dv0 = 0.f, dv1 = 0.f, dv2 = 0.f;

    #pragma unroll 2
    for (int p = start; p < end; ++p) {
        const int j = src_ids[p];
        const float4 ue = u_env[p];
        const bf16* wr = ws_w + (size_t)p * 384;
        const float w0 = b2f(wr[f]);
        const float w1 = b2f(wr[FEAT + f]);
        const float w2 = b2f(wr[2 * FEAT + f]);
        const bf16* ph = phi + (size_t)j * 384;
        const float p0 = b2f(ph[f]);
        const float p1 = b2f(ph[FEAT + f]);
        const float p2 = b2f(ph[2 * FEAT + f]);
        const float vx = LD<F32>(v_j, ((size_t)j * FEAT + f) * 3 + 0);
        const float vy = LD<F32>(v_j, ((size_t)j * FEAT + f) * 3 + 1);
        const float vz = LD<F32>(v_j, ((size_t)j * FEAT + f) * 3 + 2);
        const float i0 = w0 * p0;
        const float i1 = w1 * p1;
        const float i2 = w2 * p2;
        ds += i1;
        dv0 = fmaf(i2, ue.x, fmaf(i0, vx, dv0));
        dv1 = fmaf(i2, ue.y, fmaf(i0, vy, dv1));
        dv2 = fmaf(i2, ue.z, fmaf(i0, vz, dv2));
    }

    ST<F32>(out, (size_t)i * FEAT + f, ds);
    const size_t ob = (size_t)nN * FEAT + ((size_t)i * FEAT + f) * 3;
    ST<F32>(out, ob + 0, dv0);
    ST<F32>(out, ob + 1, dv1);
    ST<F32>(out, ob + 2, dv2);
}

__global__ __launch_bounds__(128) void msg_a_kernel(const bf16* ws_w, const bf16* phi,
        const void* v_j, const int* src_ids, const float4* u_env, const int* offsets,
        const int* __restrict__ flags, void* out, int nE, int nN) {
    if (flags[0]) msg_a_body<1>(ws_w, phi, v_j, src_ids, u_env, offsets, out, nE, nN);
    else          msg_a_body<0>(ws_w, phi, v_j, src_ids, u_env, offsets, out, nE, nN);
}

// ---------- mode C message: table-lerp w_s + 16B packed gather ----------
// Per edge per thread: 6x 2B coalesced table loads + 1x dwordx4 rec gather.
// u_env.w carries d (not env); table already folds (rbf@Wd+bd)*env.
template<int F32>
__device__ void msg_c_body(const unsigned short* __restrict__ tab, const bf16* __restrict__ rec,
        const int* __restrict__ src_ids, const float4* __restrict__ u_env,
        const int* __restrict__ offsets, void* __restrict__ out, int nE, int nN) {
    const int i = blockIdx.x;
    const int f = threadIdx.x;
    int start = offsets[i];
    int end   = offsets[i + 1];
    if (start < 0) start = 0;
    if (end > nE) end = nE;

    float ds = 0.f, dv0 = 0.f, dv1 = 0.f, dv2 = 0.f;

    for (int p = start; p < end; ++p) {
        const int j = src_ids[p];
        const float4 ue = u_env[p];
        const float d = ue.w;
        const float binf = d * INV_H;
        int bin = (int)binf;
        if (bin > NB - 2) bin = NB - 2;
        const float fr = binf - (float)bin;
        const float m = (d < CUTOFF_F) ? 1.0f : 0.0f;

        const unsigned short* T = tab + (size_t)bin * 384;
        const float t00 = us2f(T[f]);
        const float t01 = us2f(T[384 + f]);
        const float t10 = us2f(T[FEAT + f]);
        const float t11 = us2f(T[384 + FEAT + f]);
        const float t20 = us2f(T[2 * FEAT + f]);
        const float t21 = us2f(T[384 + 2 * FEAT + f]);
        const float w0 = fmaf(t01 - t00, fr, t00) * m;
        const float w1 = fmaf(t11 - t10, fr, t10) * m;
        const float w2 = fmaf(t21 - t20, fr, t20) * m;

        // one 16B gather: {phi0,phi1,phi2,pad, vx,vy,vz,pad} bf16
        const uint4 rv = *(const uint4*)(rec + ((size_t)j * FEAT + f) * 8);
        const float p0 = __uint_as_float(rv.x << 16);
        const float p1 = __uint_as_float(rv.x & 0xffff0000u);
        const float p2 = __uint_as_float(rv.y << 16);
        const float vx = __uint_as_float(rv.z << 16);
        const float vy = __uint_as_float(rv.z & 0xffff0000u);
        const float vz = __uint_as_float(rv.w << 16);

        const float i0 = w0 * p0;
        const float i1 = w1 * p1;
        const float i2 = w2 * p2;
        ds += i1;
        dv0 = fmaf(i2, ue.x, fmaf(i0, vx, dv0));
        dv1 = fmaf(i2, ue.y, fmaf(i0, vy, dv1));
        dv2 = fmaf(i2, ue.z, fmaf(i0, vz, dv2));
    }

    ST<F32>(out, (size_t)i * FEAT + f, ds);
    const size_t ob = (size_t)nN * FEAT + ((size_t)i * FEAT + f) * 3;
    ST<F32>(out, ob + 0, dv0);
    ST<F32>(out, ob + 1, dv1);
    ST<F32>(out, ob + 2, dv2);
}

__global__ __launch_bounds__(128) void msg_c_kernel(const unsigned short* tab, const bf16* rec,
        const int* src_ids, const float4* u_env, const int* offsets,
        const int* __restrict__ flags, void* out, int nE, int nN) {
    if (flags[0]) msg_c_body<1>(tab, rec, src_ids, u_env, offsets, out, nE, nN);
    else          msg_c_body<0>(tab, rec, src_ids, u_env, offsets, out, nE, nN);
}

// ---------- mode B message (exact R0 baseline fallback) ----------
template<int F32>
__device__ void msg_b_body(const void* __restrict__ v_j, const void* __restrict__ Wd,
        const void* __restrict__ bd, const bf16* __restrict__ phi,
        const float* __restrict__ gbuf, const int* __restrict__ src_ids,
        const float4* __restrict__ u_env, const int* __restrict__ offsets,
        void* __restrict__ out, int nE, int nN) {
    const int i = blockIdx.x;
    const int f = threadIdx.x;

    float wd0[NRBF], wd1[NRBF], wd2[NRBF];
    #pragma unroll
    for (int k = 0; k < NRBF; ++k) {
        wd0[k] = LD<F32>(Wd, (size_t)k * 384 + f);
        wd1[k] = LD<F32>(Wd, (size_t)k * 384 + FEAT + f);
        wd2[k] = LD<F32>(Wd, (size_t)k * 384 + 2 * FEAT + f);
    }
    const float bd0 = LD<F32>(bd, f);
    const float bd1 = LD<F32>(bd, FEAT + f);
    const float bd2 = LD<F32>(bd, 2 * FEAT + f);

    int start = offsets[i];
    int end   = offsets[i + 1];
    if (start < 0) start = 0;
    if (end > nE) end = nE;

    float ds = 0.f, dv0 = 0.f, dv1 = 0.f, dv2 = 0.f;

    for (int p = start; p < end; ++p) {
        const int j = src_ids[p];
        const float4 ue = u_env[p];
        const float* g = gbuf + (size_t)p * NRBF;
        float t0 = 0.f, t1 = 0.f, t2 = 0.f;
        #pragma unroll
        for (int k = 0; k < NRBF; ++k) {
            const float gk = g[k];
            t0 = fmaf(gk, wd0[k], t0);
            t1 = fmaf(gk, wd1[k], t1);
            t2 = fmaf(gk, wd2[k], t2);
        }
        const float w0 = fmaf(bd0, ue.w, t0);
        const float w1 = fmaf(bd1, ue.w, t1);
        const float w2 = fmaf(bd2, ue.w, t2);

        const bf16* ph = phi + (size_t)j * 384;
        const float p0 = b2f(ph[f]);
        const float p1 = b2f(ph[FEAT + f]);
        const float p2 = b2f(ph[2 * FEAT + f]);
        const float vx = LD<F32>(v_j, ((size_t)j * FEAT + f) * 3 + 0);
        const float vy = LD<F32>(v_j, ((size_t)j * FEAT + f) * 3 + 1);
        const float vz = LD<F32>(v_j, ((size_t)j * FEAT + f) * 3 + 2);

        const float i0 = w0 * p0;
        const float i1 = w1 * p1;
        const float i2 = w2 * p2;
        ds += i1;
        dv0 = fmaf(i2, ue.x, fmaf(i0, vx, dv0));
        dv1 = fmaf(i2, ue.y, fmaf(i0, vy, dv1));
        dv2 = fmaf(i2, ue.z, fmaf(i0, vz, dv2));
    }

    ST<F32>(out, (size_t)i * FEAT + f, ds);
    const size_t ob = (size_t)nN * FEAT + ((size_t)i * FEAT + f) * 3;
    ST<F32>(out, ob + 0, dv0);
    ST<F32>(out, ob + 1, dv1);
    ST<F32>(out, ob + 2, dv2);
}

__global__ __launch_bounds__(128) void msg_b_kernel(const void* v_j, const void* Wd,
        const void* bd, const bf16* phi, const float* gbuf, const int* src_ids,
        const float4* u_env, const int* offsets, const int* __restrict__ flags,
        void* out, int nE, int nN) {
    if (flags[0]) msg_b_body<1>(v_j, Wd, bd, phi, gbuf, src_ids, u_env, offsets, out, nE, nN);
    else          msg_b_body<0>(v_j, Wd, bd, phi, gbuf, src_ids, u_env, offsets, out, nE, nN);
}

extern "C" void kernel_launch(void* const* d_in, const int* in_sizes, int n_in,
                              void* d_out, int out_size, void* d_ws, size_t ws_size,
                              hipStream_t stream) {
    const void* s_j  = d_in[0];
    const void* v_j  = d_in[1];
    const void* r_ij = d_in[2];
    const int*  nbrs = (const int*)d_in[3];
    const void* W1   = d_in[4];
    const void* b1   = d_in[5];
    const void* W2   = d_in[6];
    const void* b2   = d_in[7];
    const void* Wd   = d_in[8];
    const void* bd   = d_in[9];

    const int nN = out_size / (4 * FEAT);   // 20000
    const int nE = in_sizes[2] / 3;         // 640000

    char* ws = (char*)d_ws;
    size_t off = 0;
    auto alloc = [&](size_t bytes) -> void* {
        void* p = ws + off;
        off = (off + bytes + 255) & ~(size_t)255;
        return p;
    };
    int*    flags    = (int*)alloc(16);
    int*    counts   = (int*)alloc((size_t)nN * 4);
    int*    offsets  = (int*)alloc(((size_t)nN + 1) * 4);
    int*    cursor   = (int*)alloc((size_t)nN * 4);
    int*    src_ids  = (int*)alloc((size_t)nE * 4);
    float4* u_env    = (float4*)alloc((size_t)nE * 16);
    float*  WdT      = (float*)alloc((size_t)384 * 24 * 4);
    const size_t base = off;

    // mode A layout: pos_of_e | phi | ws_w
    size_t offA = base;
    int*  pos_of_e = (int*)(ws + offA);  offA += ((size_t)nE * 4 + 255) & ~(size_t)255;
    bf16* phiA     = (bf16*)(ws + offA); offA += ((size_t)nN * 384 * 2 + 255) & ~(size_t)255;
    bf16* ws_w     = (bf16*)(ws + offA); offA += (size_t)nE * 384 * 2;
    // mode C layout: rec | tab
    size_t offC = base;
    bf16* rec = (bf16*)(ws + offC);      offC += ((size_t)nN * FEAT * 8 * 2 + 255) & ~(size_t)255;
    bf16* tab = (bf16*)(ws + offC);      offC += (size_t)NB * 384 * 2;
    // mode B layout: gbuf | phi
    size_t offB = base;
    float* gbufB = (float*)(ws + offB);  offB += ((size_t)nE * NRBF * 4 + 255) & ~(size_t)255;
    bf16*  phiB  = (bf16*)(ws + offB);   offB += (size_t)nN * 384 * 2;

    const int modeA = (ws_size >= offA) ? 1 : 0;
    const int modeC = (!modeA && ws_size >= offC) ? 1 : 0;

    init_kernel<<<(nN + 255) / 256, 256, 0, stream>>>(s_j, nbrs, nE, flags, counts, nN);
    hist_kernel<<<(nE + 255) / 256, 256, 0, stream>>>(nbrs, flags, counts, nE, nN);
    scan_kernel<<<1, 1024, 0, stream>>>(counts, offsets, cursor, nN);
    prep_kernel<<<1, 384, 0, stream>>>(Wd, bd, WdT, flags);

    const int psMode = modeA ? 1 : (modeC ? 2 : 0);
    pre_scatter_kernel<<<(nE + 255) / 256, 256, 0, stream>>>(
        r_ij, nbrs, flags, cursor, src_ids, u_env, pos_of_e, gbufB, nE, nN, psMode);

    if (modeA) {
        gemm_node_kernel<<<(nN + 7) / 8, 384, 0, stream>>>(s_j, W1, b1, W2, b2, phiA, flags, nN, 0);
        pre_ws_kernel<<<(nE + 255) / 256, 256, 0, stream>>>(r_ij, WdT, pos_of_e, ws_w, flags, nE);
        msg_a_kernel<<<nN, 128, 0, stream>>>(ws_w, phiA, v_j, src_ids, u_env, offsets,
                                             flags, d_out, nE, nN);
    } else if (modeC) {
        build_table_kernel<<<NB, 384, 0, stream>>>(WdT, tab);
        gemm_node_kernel<<<(nN + 7) / 8, 384, 0, stream>>>(s_j, W1, b1, W2, b2, rec, flags, nN, 1);
        pack_v_kernel<<<((nN * FEAT) + 255) / 256, 256, 0, stream>>>(v_j, rec, flags, nN);
        msg_c_kernel<<<nN, 128, 0, stream>>>((const unsigned short*)tab, rec, src_ids, u_env,
                                             offsets, flags, d_out, nE, nN);
    } else {
        gemm_node_kernel<<<(nN + 7) / 8, 384, 0, stream>>>(s_j, W1, b1, W2, b2, phiB, flags, nN, 0);
        msg_b_kernel<<<nN, 128, 0, stream>>>(v_j, Wd, bd, phiB, gbufB, src_ids, u_env,
                                             offsets, flags, d_out, nE, nN);
    }
}

// Round 9
// 504.018 us; speedup vs baseline: 1.1105x; 1.0688x over previous
//
#include <hip/hip_runtime.h>
#include <hip/hip_bf16.h>
#include <math.h>

typedef __hip_bfloat16 bf16;

#define FEAT 128
#define NRBF 20
#define CUTOFF_F 5.0f
#define KSCALE 0.62831853071795864769f  // pi / 5
#define NB 4096
#define INV_H 819.0f                    // (NB-1)/CUTOFF
#define H_STEP 0.001221001221001221f    // CUTOFF/(NB-1)

__device__ __forceinline__ float b2f(bf16 x) { return __bfloat162float(x); }
__device__ __forceinline__ bf16 f2b(float x) { return __float2bfloat16(x); }
__device__ __forceinline__ float us2f(unsigned short u) {
    return __uint_as_float(((unsigned)u) << 16);
}

template<int F32>
__device__ __forceinline__ float LD(const void* p, size_t i) {
    if (F32) return ((const float*)p)[i];
    return b2f(((const bf16*)p)[i]);
}
template<int F32>
__device__ __forceinline__ void ST(void* p, size_t i, float v) {
    if (F32) ((float*)p)[i] = v;
    else ((bf16*)p)[i] = f2b(v);
}

__device__ __forceinline__ int get_dst(const int* nb, int e, int is64) {
    return is64 ? nb[4 * e] : nb[2 * e];
}
__device__ __forceinline__ int get_src(const int* nb, int e, int is64) {
    return is64 ? nb[4 * e + 2] : nb[2 * e + 1];
}
__device__ __forceinline__ int clampi(int v, int n) {
    return v < 0 ? 0 : (v >= n ? n - 1 : v);
}

// ---------- init: zero counts + sniff dtypes ----------
__global__ void init_kernel(const void* __restrict__ s_ptr, const int* __restrict__ nbrs32,
                            int nE, int* __restrict__ flags, int* __restrict__ counts, int nN) {
    int t = blockIdx.x * blockDim.x + threadIdx.x;
    if (t < nN) counts[t] = 0;
    if (t == 0) {
        const unsigned* u = (const unsigned*)s_ptr;
        int hits = 0;
        for (int i = 0; i < 64; ++i) {
            unsigned ef = (u[i] >> 7) & 0xFF;
            hits += (ef >= 110 && ef <= 135) ? 1 : 0;
        }
        flags[0] = (hits < 32) ? 1 : 0;   // 1 => f32 inputs
        int lim = 2 * nE; if (lim > 128) lim = 128;
        int allz = 1;
        for (int i = 1; i < lim; i += 2) allz &= (nbrs32[i] == 0);
        flags[1] = allz;                   // 1 => int64 nbrs
    }
}

// ---------- CSR build ----------
__global__ void hist_kernel(const int* __restrict__ nbrs, const int* __restrict__ flags,
                            int* __restrict__ counts, int nE, int nN) {
    int e = blockIdx.x * blockDim.x + threadIdx.x;
    if (e < nE) {
        int d = clampi(get_dst(nbrs, e, flags[1]), nN);
        atomicAdd(&counts[d], 1);
    }
}

__global__ __launch_bounds__(1024) void scan_kernel(const int* __restrict__ counts,
        int* __restrict__ offsets, int* __restrict__ cursor, int nN) {
    __shared__ int part[1024];
    const int t = threadIdx.x;
    const int chunk = (nN + 1023) / 1024;
    const int base = t * chunk;
    int local[32];
    int sum = 0;
    for (int c = 0; c < chunk && c < 32; ++c) {
        int idx = base + c;
        int v = (idx < nN) ? counts[idx] : 0;
        local[c] = v;
        sum += v;
    }
    part[t] = sum;
    __syncthreads();
    for (int off = 1; off < 1024; off <<= 1) {
        int add = (t >= off) ? part[t - off] : 0;
        __syncthreads();
        part[t] += add;
        __syncthreads();
    }
    int run = part[t] - sum;
    for (int c = 0; c < chunk && c < 32; ++c) {
        int idx = base + c;
        if (idx < nN) { offsets[idx] = run; cursor[idx] = run; run += local[c]; }
    }
    if (t == 1023) offsets[nN] = part[1023];
}

// ---------- prep: WdT[c][0..19] = Wd[k][c] (f32), WdT[c][20] = bd[c]; rows padded to 24 ----------
__global__ __launch_bounds__(384) void prep_kernel(const void* __restrict__ Wd,
        const void* __restrict__ bd, float* __restrict__ WdT, const int* __restrict__ flags) {
    const int c = threadIdx.x;
    const int F32 = flags[0];
    if (F32) {
        for (int k = 0; k < NRBF; ++k) WdT[c * 24 + k] = ((const float*)Wd)[k * 384 + c];
        WdT[c * 24 + 20] = ((const float*)bd)[c];
    } else {
        for (int k = 0; k < NRBF; ++k) WdT[c * 24 + k] = b2f(((const bf16*)Wd)[k * 384 + c]);
        WdT[c * 24 + 20] = b2f(((const bf16*)bd)[c]);
    }
    WdT[c * 24 + 21] = 0.f; WdT[c * 24 + 22] = 0.f; WdT[c * 24 + 23] = 0.f;
}

// ---------- mode C: w_s lookup table over distance ----------
// tab[b][c] = (rbf(d_b)@Wd + bd)[c] * env(d_b),  d_b = b*H_STEP, bf16
__global__ __launch_bounds__(384) void build_table_kernel(const float* __restrict__ WdT,
        bf16* __restrict__ tab) {
    const int b = blockIdx.x;
    const int c = threadIdx.x;
    const float d = fmaxf(b * H_STEP, 1e-7f);
    const float x = d * KSCALE;
    const float s1 = sinf(x);
    const float c1 = cosf(x);
    const float env = (d < CUTOFF_F) ? (0.5f * (c1 + 1.0f)) : 0.0f;
    const float invd = 1.0f / d;
    float g[NRBF];
    const float tc = 2.0f * c1;
    float skm2 = 0.f, skm1 = s1;
    g[0] = s1 * invd;
    #pragma unroll
    for (int k = 1; k < NRBF; ++k) {
        const float sk = fmaf(tc, skm1, -skm2);
        g[k] = sk * invd;
        skm2 = skm1; skm1 = sk;
    }
    const float* w = WdT + (size_t)c * 24;
    float acc = w[20];                      // bd
    #pragma unroll
    for (int k = 0; k < NRBF; ++k) acc = fmaf(g[k], w[k], acc);
    tab[(size_t)b * 384 + c] = f2b(acc * env);
}

// ---------- scatter + per-position side records ----------
// MODE 0 (B): src_ids + u_env{unit,env} + gbuf (trig here)
// MODE 1 (A): src_ids + u_env{unit,env} + pos_of_e (trig here)
// MODE 2 (C): src_ids + epos ONLY (8B/edge scattered; no r_ij read at all)
template<int F32, int MODE>
__device__ void pre_scatter_body(const void* __restrict__ r_ij, const int* __restrict__ nbrs,
        int is64, int* __restrict__ cursor, int* __restrict__ src_ids,
        float4* __restrict__ u_env, int* __restrict__ pos_of_e, float* __restrict__ gbuf,
        int* __restrict__ epos, int e, int nE, int nN) {
    const int d = clampi(get_dst(nbrs, e, is64), nN);
    const int j = clampi(get_src(nbrs, e, is64), nN);
    int pos = atomicAdd(&cursor[d], 1);
    pos = clampi(pos, nE);
    src_ids[pos] = j;

    if (MODE == 2) {
        epos[pos] = e;
        return;
    }

    const float rx = LD<F32>(r_ij, (size_t)3 * e + 0);
    const float ry = LD<F32>(r_ij, (size_t)3 * e + 1);
    const float rz = LD<F32>(r_ij, (size_t)3 * e + 2);
    const float d2   = rx * rx + ry * ry + rz * rz + 3e-15f;
    const float invd = rsqrtf(d2);
    const float dd   = d2 * invd;
    const float x  = dd * KSCALE;
    const float c1 = F32 ? cosf(x) : __cosf(x);
    const float env = (dd < CUTOFF_F) ? (0.5f * (c1 + 1.0f)) : 0.0f;
    u_env[pos] = make_float4(rx * invd, ry * invd, rz * invd, env);

    if (MODE == 1) {
        pos_of_e[e] = pos;
    } else {
        const float s1 = F32 ? sinf(x) : __sinf(x);
        const float scale = invd * env;
        const float tc = 2.0f * c1;
        float skm2 = 0.f, skm1 = s1;
        float* g = gbuf + (size_t)pos * NRBF;
        g[0] = s1 * scale;
        #pragma unroll
        for (int k = 1; k < NRBF; ++k) {
            const float sk = fmaf(tc, skm1, -skm2);
            g[k] = sk * scale;
            skm2 = skm1; skm1 = sk;
        }
    }
}

__global__ __launch_bounds__(256) void pre_scatter_kernel(const void* r_ij, const int* nbrs,
        const int* __restrict__ flags, int* cursor, int* src_ids, float4* u_env,
        int* pos_of_e, float* gbuf, int* epos, int nE, int nN, int mode) {
    int e = blockIdx.x * blockDim.x + threadIdx.x;
    if (e >= nE) return;
    const int F32 = flags[0], is64 = flags[1];
    if (mode == 2) {
        if (F32) pre_scatter_body<1,2>(r_ij, nbrs, is64, cursor, src_ids, u_env, pos_of_e, gbuf, epos, e, nE, nN);
        else     pre_scatter_body<0,2>(r_ij, nbrs, is64, cursor, src_ids, u_env, pos_of_e, gbuf, epos, e, nE, nN);
    } else if (mode == 1) {
        if (F32) pre_scatter_body<1,1>(r_ij, nbrs, is64, cursor, src_ids, u_env, pos_of_e, gbuf, epos, e, nE, nN);
        else     pre_scatter_body<0,1>(r_ij, nbrs, is64, cursor, src_ids, u_env, pos_of_e, gbuf, epos, e, nE, nN);
    } else {
        if (F32) pre_scatter_body<1,0>(r_ij, nbrs, is64, cursor, src_ids, u_env, pos_of_e, gbuf, epos, e, nE, nN);
        else     pre_scatter_body<0,0>(r_ij, nbrs, is64, cursor, src_ids, u_env, pos_of_e, gbuf, epos, e, nE, nN);
    }
}

// ---------- fused node MLP: phi = silu(s@W1+b1)@W2 + b2 ----------
// packed=1: rec[node][f][6] slots 0..2 = phi012, slots 3..5 = v_j (bf16) [pack_v fused]
template<int F32>
__device__ void gemm_body(const void* __restrict__ s_j, const void* __restrict__ v_j,
                          const void* __restrict__ W1,
                          const void* __restrict__ b1, const void* __restrict__ W2,
                          const void* __restrict__ b2v, bf16* __restrict__ phi, int nN,
                          int packed) {
    __shared__ float sl[8][FEAT];
    __shared__ float hl[8][FEAT];
    const int t = threadIdx.x;
    const int n0 = blockIdx.x * 8;
    const int fch  = t & 127;
    const int comp = t >> 7;

    if (packed) {
        // fused v-pack: thread (fch, comp) writes v_j[row][fch][comp] to rec slot 3+comp
        #pragma unroll
        for (int n = 0; n < 8; ++n) {
            int row = n0 + n;
            if (row < nN) {
                const float vv = LD<F32>(v_j, ((size_t)row * FEAT + fch) * 3 + comp);
                phi[((size_t)row * FEAT + fch) * 6 + 3 + comp] = f2b(vv);
            }
        }
    }

    for (int idx = t; idx < 8 * FEAT; idx += 384) {
        int n = idx >> 7, k = idx & 127;
        int row = n0 + n;
        sl[n][k] = (row < nN) ? LD<F32>(s_j, (size_t)row * FEAT + k) : 0.f;
    }
    __syncthreads();
    for (int idx = t; idx < 8 * FEAT; idx += 384) {
        int n = idx >> 7, f = idx & 127;
        float a = 0.f;
        #pragma unroll 4
        for (int k = 0; k < FEAT; ++k) a = fmaf(sl[n][k], LD<F32>(W1, (size_t)k * FEAT + f), a);
        a += LD<F32>(b1, f);
        float sg = F32 ? (1.0f / (1.0f + expf(-a))) : (1.0f / (1.0f + __expf(-a)));
        hl[n][f] = a * sg;
    }
    __syncthreads();
    float acc[8] = {};
    #pragma unroll 4
    for (int k = 0; k < FEAT; ++k) {
        const float w = LD<F32>(W2, (size_t)k * 384 + t);
        #pragma unroll
        for (int n = 0; n < 8; ++n) acc[n] = fmaf(hl[n][k], w, acc[n]);
    }
    const float bb = LD<F32>(b2v, t);
    #pragma unroll
    for (int n = 0; n < 8; ++n) {
        int row = n0 + n;
        if (row < nN) {
            if (packed) phi[((size_t)row * FEAT + fch) * 6 + comp] = f2b(acc[n] + bb);
            else        phi[(size_t)row * 384 + t] = f2b(acc[n] + bb);
        }
    }
}

__global__ __launch_bounds__(384) void gemm_node_kernel(const void* s_j, const void* v_j,
        const void* W1, const void* b1, const void* W2, const void* b2v, bf16* phi,
        const int* __restrict__ flags, int nN, int packed) {
    if (flags[0]) gemm_body<1>(s_j, v_j, W1, b1, W2, b2v, phi, nN, packed);
    else          gemm_body<0>(s_j, v_j, W1, b1, W2, b2v, phi, nN, packed);
}

// ---------- mode A: per-edge w_s GEMM ----------
template<int F32>
__device__ void pre_ws_body(const void* __restrict__ r_ij, const float* __restrict__ WdT,
        const int* __restrict__ pos_of_e, bf16* __restrict__ ws_w, int e) {
    const float rx = LD<F32>(r_ij, (size_t)3 * e + 0);
    const float ry = LD<F32>(r_ij, (size_t)3 * e + 1);
    const float rz = LD<F32>(r_ij, (size_t)3 * e + 2);
    const float d2   = rx * rx + ry * ry + rz * rz + 3e-15f;
    const float invd = rsqrtf(d2);
    const float dd   = d2 * invd;
    const float x  = dd * KSCALE;
    const float s1 = F32 ? sinf(x) : __sinf(x);
    const float c1 = F32 ? cosf(x) : __cosf(x);
    const float env = (dd < CUTOFF_F) ? (0.5f * (c1 + 1.0f)) : 0.0f;
    const float scale = invd * env;
    float gk[NRBF];
    const float tc = 2.0f * c1;
    float skm2 = 0.f, skm1 = s1;
    gk[0] = s1 * scale;
    #pragma unroll
    for (int k = 1; k < NRBF; ++k) {
        const float sk = fmaf(tc, skm1, -skm2);
        gk[k] = sk * scale;
        skm2 = skm1; skm1 = sk;
    }
    const int pos = pos_of_e[e];
    bf16* dst = ws_w + (size_t)pos * 384;
    for (int c0 = 0; c0 < 384; c0 += 4) {
        float r[4];
        #pragma unroll
        for (int u = 0; u < 4; ++u) {
            const float* w = WdT + (size_t)(c0 + u) * 24;
            float acc = w[20] * env;
            #pragma unroll
            for (int k = 0; k < NRBF; ++k) acc = fmaf(gk[k], w[k], acc);
            r[u] = acc;
        }
        union { bf16 b[4]; uint2 u2; } pk;
        pk.b[0] = f2b(r[0]); pk.b[1] = f2b(r[1]); pk.b[2] = f2b(r[2]); pk.b[3] = f2b(r[3]);
        *(uint2*)(dst + c0) = pk.u2;
    }
}

__global__ __launch_bounds__(256) void pre_ws_kernel(const void* r_ij,
        const float* __restrict__ WdT, const int* __restrict__ pos_of_e,
        bf16* __restrict__ ws_w, const int* __restrict__ flags, int nE) {
    int e = blockIdx.x * blockDim.x + threadIdx.x;
    if (e >= nE) return;
    if (flags[0]) pre_ws_body<1>(r_ij, WdT, pos_of_e, ws_w, e);
    else          pre_ws_body<0>(r_ij, WdT, pos_of_e, ws_w, e);
}

// ---------- mode A message: pure gather-accumulate ----------
template<int F32>
__device__ void msg_a_body(const bf16* __restrict__ ws_w, const bf16* __restrict__ phi,
        const void* __restrict__ v_j, const int* __restrict__ src_ids,
        const float4* __restrict__ u_env, const int* __restrict__ offsets,
        void* __restrict__ out, int nE, int nN) {
    const int i = blockIdx.x;
    const int f = threadIdx.x;
    int start = offsets[i];
    int end   = offsets[i + 1];
    if (start < 0) start = 0;
    if (end > nE) end = nE;

    float ds = 0.f, dv0 = 0.f, dv1 = 0.f, dv2 = 0.f;

    #pragma unroll 2
    for (int p = start; p < end; ++p) {
        const int j = src_ids[p];
        const float4 ue = u_env[p];
        const bf16* wr = ws_w + (size_t)p * 384;
        const float w0 = b2f(wr[f]);
        const float w1 = b2f(wr[FEAT + f]);
        const float w2 = b2f(wr[2 * FEAT + f]);
        const bf16* ph = phi + (size_t)j * 384;
        const float p0 = b2f(ph[f]);
        const float p1 = b2f(ph[FEAT + f]);
        const float p2 = b2f(ph[2 * FEAT + f]);
        const float vx = LD<F32>(v_j, ((size_t)j * FEAT + f) * 3 + 0);
        const float vy = LD<F32>(v_j, ((size_t)j * FEAT + f) * 3 + 1);
        const float vz = LD<F32>(v_j, ((size_t)j * FEAT + f) * 3 + 2);
        const float i0 = w0 * p0;
        const float i1 = w1 * p1;
        const float i2 = w2 * p2;
        ds += i1;
        dv0 = fmaf(i2, ue.x, fmaf(i0, vx, dv0));
        dv1 = fmaf(i2, ue.y, fmaf(i0, vy, dv1));
        dv2 = fmaf(i2, ue.z, fmaf(i0, vz, dv2));
    }

    ST<F32>(out, (size_t)i * FEAT + f, ds);
    const size_t ob = (size_t)nN * FEAT + ((size_t)i * FEAT + f) * 3;
    ST<F32>(out, ob + 0, dv0);
    ST<F32>(out, ob + 1, dv1);
    ST<F32>(out, ob + 2, dv2);
}

__global__ __launch_bounds__(128) void msg_a_kernel(const bf16* ws_w, const bf16* phi,
        const void* v_j, const int* src_ids, const float4* u_env, const int* offsets,
        const int* __restrict__ flags, void* out, int nE, int nN) {
    if (flags[0]) msg_a_body<1>(ws_w, phi, v_j, src_ids, u_env, offsets, out, nE, nN);
    else          msg_a_body<0>(ws_w, phi, v_j, src_ids, u_env, offsets, out, nE, nN);
}

// ---------- mode C message: table-lerp w_s + 12B packed gather; unit/d from r_ij ----------
// Per edge per thread: 3 dword rec gather (12B) + 6x 2B table loads + wave-uniform r_ij read.
template<int F32>
__device__ void msg_c_body(const unsigned short* __restrict__ tab, const bf16* __restrict__ rec,
        const void* __restrict__ r_ij, const int* __restrict__ src_ids,
        const int* __restrict__ epos, const int* __restrict__ offsets,
        void* __restrict__ out, int nE, int nN) {
    const int i = blockIdx.x;
    const int f = threadIdx.x;
    int start = offsets[i];
    int end   = offsets[i + 1];
    if (start < 0) start = 0;
    if (end > nE) end = nE;

    float ds = 0.f, dv0 = 0.f, dv1 = 0.f, dv2 = 0.f;

    for (int p = start; p < end; ++p) {
        const int j = src_ids[p];
        const int e = clampi(epos[p], nE);
        const float rx = LD<F32>(r_ij, (size_t)3 * e + 0);
        const float ry = LD<F32>(r_ij, (size_t)3 * e + 1);
        const float rz = LD<F32>(r_ij, (size_t)3 * e + 2);
        const float d2   = rx * rx + ry * ry + rz * rz + 3e-15f;
        const float invd = rsqrtf(d2);
        const float dd   = d2 * invd;
        const float ux = rx * invd, uy = ry * invd, uz = rz * invd;

        const float binf = dd * INV_H;
        int bin = (int)binf;
        if (bin > NB - 2) bin = NB - 2;
        const float fr = binf - (float)bin;
        const float m = (dd < CUTOFF_F) ? 1.0f : 0.0f;

        const unsigned short* T = tab + (size_t)bin * 384;
        const float t00 = us2f(T[f]);
        const float t01 = us2f(T[384 + f]);
        const float t10 = us2f(T[FEAT + f]);
        const float t11 = us2f(T[384 + FEAT + f]);
        const float t20 = us2f(T[2 * FEAT + f]);
        const float t21 = us2f(T[384 + 2 * FEAT + f]);
        const float w0 = fmaf(t01 - t00, fr, t00) * m;
        const float w1 = fmaf(t11 - t10, fr, t10) * m;
        const float w2 = fmaf(t21 - t20, fr, t20) * m;

        // 12B gather: {phi0,phi1,phi2,vx,vy,vz} bf16, 4B-aligned
        const unsigned* rp = (const unsigned*)(rec + ((size_t)j * FEAT + f) * 6);
        const unsigned ra = rp[0];
        const unsigned rb = rp[1];
        const unsigned rc = rp[2];
        const float p0 = __uint_as_float(ra << 16);
        const float p1 = __uint_as_float(ra & 0xffff0000u);
        const float p2 = __uint_as_float(rb << 16);
        const float vx = __uint_as_float(rb & 0xffff0000u);
        const float vy = __uint_as_float(rc << 16);
        const float vz = __uint_as_float(rc & 0xffff0000u);

        const float i0 = w0 * p0;
        const float i1 = w1 * p1;
        const float i2 = w2 * p2;
        ds += i1;
        dv0 = fmaf(i2, ux, fmaf(i0, vx, dv0));
        dv1 = fmaf(i2, uy, fmaf(i0, vy, dv1));
        dv2 = fmaf(i2, uz, fmaf(i0, vz, dv2));
    }

    ST<F32>(out, (size_t)i * FEAT + f, ds);
    const size_t ob = (size_t)nN * FEAT + ((size_t)i * FEAT + f) * 3;
    ST<F32>(out, ob + 0, dv0);
    ST<F32>(out, ob + 1, dv1);
    ST<F32>(out, ob + 2, dv2);
}

__global__ __launch_bounds__(128) void msg_c_kernel(const unsigned short* tab, const bf16* rec,
        const void* r_ij, const int* src_ids, const int* epos, const int* offsets,
        const int* __restrict__ flags, void* out, int nE, int nN) {
    if (flags[0]) msg_c_body<1>(tab, rec, r_ij, src_ids, epos, offsets, out, nE, nN);
    else          msg_c_body<0>(tab, rec, r_ij, src_ids, epos, offsets, out, nE, nN);
}

// ---------- mode B message (exact R0 baseline fallback) ----------
template<int F32>
__device__ void msg_b_body(const void* __restrict__ v_j, const void* __restrict__ Wd,
        const void* __restrict__ bd, const bf16* __restrict__ phi,
        const float* __restrict__ gbuf, const int* __restrict__ src_ids,
        const float4* __restrict__ u_env, const int* __restrict__ offsets,
        void* __restrict__ out, int nE, int nN) {
    const int i = blockIdx.x;
    const int f = threadIdx.x;

    float wd0[NRBF], wd1[NRBF], wd2[NRBF];
    #pragma unroll
    for (int k = 0; k < NRBF; ++k) {
        wd0[k] = LD<F32>(Wd, (size_t)k * 384 + f);
        wd1[k] = LD<F32>(Wd, (size_t)k * 384 + FEAT + f);
        wd2[k] = LD<F32>(Wd, (size_t)k * 384 + 2 * FEAT + f);
    }
    const float bd0 = LD<F32>(bd, f);
    const float bd1 = LD<F32>(bd, FEAT + f);
    const float bd2 = LD<F32>(bd, 2 * FEAT + f);

    int start = offsets[i];
    int end   = offsets[i + 1];
    if (start < 0) start = 0;
    if (end > nE) end = nE;

    float ds = 0.f, dv0 = 0.f, dv1 = 0.f, dv2 = 0.f;

    for (int p = start; p < end; ++p) {
        const int j = src_ids[p];
        const float4 ue = u_env[p];
        const float* g = gbuf + (size_t)p * NRBF;
        float t0 = 0.f, t1 = 0.f, t2 = 0.f;
        #pragma unroll
        for (int k = 0; k < NRBF; ++k) {
            const float gk = g[k];
            t0 = fmaf(gk, wd0[k], t0);
            t1 = fmaf(gk, wd1[k], t1);
            t2 = fmaf(gk, wd2[k], t2);
        }
        const float w0 = fmaf(bd0, ue.w, t0);
        const float w1 = fmaf(bd1, ue.w, t1);
        const float w2 = fmaf(bd2, ue.w, t2);

        const bf16* ph = phi + (size_t)j * 384;
        const float p0 = b2f(ph[f]);
        const float p1 = b2f(ph[FEAT + f]);
        const float p2 = b2f(ph[2 * FEAT + f]);
        const float vx = LD<F32>(v_j, ((size_t)j * FEAT + f) * 3 + 0);
        const float vy = LD<F32>(v_j, ((size_t)j * FEAT + f) * 3 + 1);
        const float vz = LD<F32>(v_j, ((size_t)j * FEAT + f) * 3 + 2);

        const float i0 = w0 * p0;
        const float i1 = w1 * p1;
        const float i2 = w2 * p2;
        ds += i1;
        dv0 = fmaf(i2, ue.x, fmaf(i0, vx, dv0));
        dv1 = fmaf(i2, ue.y, fmaf(i0, vy, dv1));
        dv2 = fmaf(i2, ue.z, fmaf(i0, vz, dv2));
    }

    ST<F32>(out, (size_t)i * FEAT + f, ds);
    const size_t ob = (size_t)nN * FEAT + ((size_t)i * FEAT + f) * 3;
    ST<F32>(out, ob + 0, dv0);
    ST<F32>(out, ob + 1, dv1);
    ST<F32>(out, ob + 2, dv2);
}

__global__ __launch_bounds__(128) void msg_b_kernel(const void* v_j, const void* Wd,
        const void* bd, const bf16* phi, const float* gbuf, const int* src_ids,
        const float4* u_env, const int* offsets, const int* __restrict__ flags,
        void* out, int nE, int nN) {
    if (flags[0]) msg_b_body<1>(v_j, Wd, bd, phi, gbuf, src_ids, u_env, offsets, out, nE, nN);
    else          msg_b_body<0>(v_j, Wd, bd, phi, gbuf, src_ids, u_env, offsets, out, nE, nN);
}

extern "C" void kernel_launch(void* const* d_in, const int* in_sizes, int n_in,
                              void* d_out, int out_size, void* d_ws, size_t ws_size,
                              hipStream_t stream) {
    const void* s_j  = d_in[0];
    const void* v_j  = d_in[1];
    const void* r_ij = d_in[2];
    const int*  nbrs = (const int*)d_in[3];
    const void* W1   = d_in[4];
    const void* b1   = d_in[5];
    const void* W2   = d_in[6];
    const void* b2   = d_in[7];
    const void* Wd   = d_in[8];
    const void* bd   = d_in[9];

    const int nN = out_size / (4 * FEAT);   // 20000
    const int nE = in_sizes[2] / 3;         // 640000

    char* ws = (char*)d_ws;
    size_t off = 0;
    auto alloc = [&](size_t bytes) -> void* {
        void* p = ws + off;
        off = (off + bytes + 255) & ~(size_t)255;
        return p;
    };
    int*    flags    = (int*)alloc(16);
    int*    counts   = (int*)alloc((size_t)nN * 4);
    int*    offsets  = (int*)alloc(((size_t)nN + 1) * 4);
    int*    cursor   = (int*)alloc((size_t)nN * 4);
    int*    src_ids  = (int*)alloc((size_t)nE * 4);
    float4* u_env    = (float4*)alloc((size_t)nE * 16);
    int*    epos     = (int*)alloc((size_t)nE * 4);
    float*  WdT      = (float*)alloc((size_t)384 * 24 * 4);
    const size_t base = off;

    // mode A layout: pos_of_e | phi | ws_w
    size_t offA = base;
    int*  pos_of_e = (int*)(ws + offA);  offA += ((size_t)nE * 4 + 255) & ~(size_t)255;
    bf16* phiA     = (bf16*)(ws + offA); offA += ((size_t)nN * 384 * 2 + 255) & ~(size_t)255;
    bf16* ws_w     = (bf16*)(ws + offA); offA += (size_t)nE * 384 * 2;
    // mode C layout: rec (12B per (node,f)) | tab
    size_t offC = base;
    bf16* rec = (bf16*)(ws + offC);      offC += ((size_t)nN * FEAT * 6 * 2 + 255) & ~(size_t)255;
    bf16* tab = (bf16*)(ws + offC);      offC += (size_t)NB * 384 * 2;
    // mode B layout: gbuf | phi
    size_t offB = base;
    float* gbufB = (float*)(ws + offB);  offB += ((size_t)nE * NRBF * 4 + 255) & ~(size_t)255;
    bf16*  phiB  = (bf16*)(ws + offB);   offB += (size_t)nN * 384 * 2;

    const int modeA = (ws_size >= offA) ? 1 : 0;
    const int modeC = (!modeA && ws_size >= offC) ? 1 : 0;

    init_kernel<<<(nN + 255) / 256, 256, 0, stream>>>(s_j, nbrs, nE, flags, counts, nN);
    hist_kernel<<<(nE + 255) / 256, 256, 0, stream>>>(nbrs, flags, counts, nE, nN);
    scan_kernel<<<1, 1024, 0, stream>>>(counts, offsets, cursor, nN);
    prep_kernel<<<1, 384, 0, stream>>>(Wd, bd, WdT, flags);

    const int psMode = modeA ? 1 : (modeC ? 2 : 0);
    pre_scatter_kernel<<<(nE + 255) / 256, 256, 0, stream>>>(
        r_ij, nbrs, flags, cursor, src_ids, u_env, pos_of_e, gbufB, epos, nE, nN, psMode);

    if (modeA) {
        gemm_node_kernel<<<(nN + 7) / 8, 384, 0, stream>>>(s_j, v_j, W1, b1, W2, b2, phiA, flags, nN, 0);
        pre_ws_kernel<<<(nE + 255) / 256, 256, 0, stream>>>(r_ij, WdT, pos_of_e, ws_w, flags, nE);
        msg_a_kernel<<<nN, 128, 0, stream>>>(ws_w, phiA, v_j, src_ids, u_env, offsets,
                                             flags, d_out, nE, nN);
    } else if (modeC) {
        build_table_kernel<<<NB, 384, 0, stream>>>(WdT, tab);
        gemm_node_kernel<<<(nN + 7) / 8, 384, 0, stream>>>(s_j, v_j, W1, b1, W2, b2, rec, flags, nN, 1);
        msg_c_kernel<<<nN, 128, 0, stream>>>((const unsigned short*)tab, rec, r_ij, src_ids,
                                             epos, offsets, flags, d_out, nE, nN);
    } else {
        gemm_node_kernel<<<(nN + 7) / 8, 384, 0, stream>>>(s_j, v_j, W1, b1, W2, b2, phiB, flags, nN, 0);
        msg_b_kernel<<<nN, 128, 0, stream>>>(v_j, Wd, bd, phiB, gbufB, src_ids, u_env,
                                             offsets, flags, d_out, nE, nN);
    }
}

// Round 10
// 500.680 us; speedup vs baseline: 1.1179x; 1.0067x over previous
//
#include <hip/hip_runtime.h>
#include <hip/hip_bf16.h>
#include <math.h>

typedef __hip_bfloat16 bf16;

#define FEAT 128
#define NRBF 20
#define CUTOFF_F 5.0f
#define KSCALE 0.62831853071795864769f  // pi / 5
#define NB 4096
#define INV_H 819.0f                    // (NB-1)/CUTOFF
#define H_STEP 0.001221001221001221f    // CUTOFF/(NB-1)

__device__ __forceinline__ float b2f(bf16 x) { return __bfloat162float(x); }
__device__ __forceinline__ bf16 f2b(float x) { return __float2bfloat16(x); }
__device__ __forceinline__ float us2f(unsigned short u) {
    return __uint_as_float(((unsigned)u) << 16);
}

template<int F32>
__device__ __forceinline__ float LD(const void* p, size_t i) {
    if (F32) return ((const float*)p)[i];
    return b2f(((const bf16*)p)[i]);
}
template<int F32>
__device__ __forceinline__ void ST(void* p, size_t i, float v) {
    if (F32) ((float*)p)[i] = v;
    else ((bf16*)p)[i] = f2b(v);
}

__device__ __forceinline__ int get_dst(const int* nb, int e, int is64) {
    return is64 ? nb[4 * e] : nb[2 * e];
}
__device__ __forceinline__ int get_src(const int* nb, int e, int is64) {
    return is64 ? nb[4 * e + 2] : nb[2 * e + 1];
}
__device__ __forceinline__ int clampi(int v, int n) {
    return v < 0 ? 0 : (v >= n ? n - 1 : v);
}

// ---------- init: zero counts + sniff dtypes ----------
__global__ void init_kernel(const void* __restrict__ s_ptr, const int* __restrict__ nbrs32,
                            int nE, int* __restrict__ flags, int* __restrict__ counts, int nN) {
    int t = blockIdx.x * blockDim.x + threadIdx.x;
    if (t < nN) counts[t] = 0;
    if (t == 0) {
        const unsigned* u = (const unsigned*)s_ptr;
        int hits = 0;
        for (int i = 0; i < 64; ++i) {
            unsigned ef = (u[i] >> 7) & 0xFF;
            hits += (ef >= 110 && ef <= 135) ? 1 : 0;
        }
        flags[0] = (hits < 32) ? 1 : 0;   // 1 => f32 inputs
        int lim = 2 * nE; if (lim > 128) lim = 128;
        int allz = 1;
        for (int i = 1; i < lim; i += 2) allz &= (nbrs32[i] == 0);
        flags[1] = allz;                   // 1 => int64 nbrs
    }
}

// ---------- CSR build ----------
__global__ void hist_kernel(const int* __restrict__ nbrs, const int* __restrict__ flags,
                            int* __restrict__ counts, int nE, int nN) {
    int e = blockIdx.x * blockDim.x + threadIdx.x;
    if (e < nE) {
        int d = clampi(get_dst(nbrs, e, flags[1]), nN);
        atomicAdd(&counts[d], 1);
    }
}

__global__ __launch_bounds__(1024) void scan_kernel(const int* __restrict__ counts,
        int* __restrict__ offsets, int* __restrict__ cursor, int nN) {
    __shared__ int part[1024];
    const int t = threadIdx.x;
    const int chunk = (nN + 1023) / 1024;
    const int base = t * chunk;
    int local[32];
    int sum = 0;
    for (int c = 0; c < chunk && c < 32; ++c) {
        int idx = base + c;
        int v = (idx < nN) ? counts[idx] : 0;
        local[c] = v;
        sum += v;
    }
    part[t] = sum;
    __syncthreads();
    for (int off = 1; off < 1024; off <<= 1) {
        int add = (t >= off) ? part[t - off] : 0;
        __syncthreads();
        part[t] += add;
        __syncthreads();
    }
    int run = part[t] - sum;
    for (int c = 0; c < chunk && c < 32; ++c) {
        int idx = base + c;
        if (idx < nN) { offsets[idx] = run; cursor[idx] = run; run += local[c]; }
    }
    if (t == 1023) offsets[nN] = part[1023];
}

// ---------- prep: WdT[c][0..19] = Wd[k][c] (f32), WdT[c][20] = bd[c]; rows padded to 24 ----------
__global__ __launch_bounds__(384) void prep_kernel(const void* __restrict__ Wd,
        const void* __restrict__ bd, float* __restrict__ WdT, const int* __restrict__ flags) {
    const int c = threadIdx.x;
    const int F32 = flags[0];
    if (F32) {
        for (int k = 0; k < NRBF; ++k) WdT[c * 24 + k] = ((const float*)Wd)[k * 384 + c];
        WdT[c * 24 + 20] = ((const float*)bd)[c];
    } else {
        for (int k = 0; k < NRBF; ++k) WdT[c * 24 + k] = b2f(((const bf16*)Wd)[k * 384 + c]);
        WdT[c * 24 + 20] = b2f(((const bf16*)bd)[c]);
    }
    WdT[c * 24 + 21] = 0.f; WdT[c * 24 + 22] = 0.f; WdT[c * 24 + 23] = 0.f;
}

// ---------- mode C: w_s lookup table over distance ----------
// tab[b][c] = (rbf(d_b)@Wd + bd)[c] * env(d_b),  d_b = b*H_STEP, bf16
__global__ __launch_bounds__(384) void build_table_kernel(const float* __restrict__ WdT,
        bf16* __restrict__ tab) {
    const int b = blockIdx.x;
    const int c = threadIdx.x;
    const float d = fmaxf(b * H_STEP, 1e-7f);
    const float x = d * KSCALE;
    const float s1 = sinf(x);
    const float c1 = cosf(x);
    const float env = (d < CUTOFF_F) ? (0.5f * (c1 + 1.0f)) : 0.0f;
    const float invd = 1.0f / d;
    float g[NRBF];
    const float tc = 2.0f * c1;
    float skm2 = 0.f, skm1 = s1;
    g[0] = s1 * invd;
    #pragma unroll
    for (int k = 1; k < NRBF; ++k) {
        const float sk = fmaf(tc, skm1, -skm2);
        g[k] = sk * invd;
        skm2 = skm1; skm1 = sk;
    }
    const float* w = WdT + (size_t)c * 24;
    float acc = w[20];                      // bd
    #pragma unroll
    for (int k = 0; k < NRBF; ++k) acc = fmaf(g[k], w[k], acc);
    tab[(size_t)b * 384 + c] = f2b(acc * env);
}

// ---------- scatter + per-position side records ----------
// MODE 0 (B): src_ids + u_env{unit,env} + gbuf (trig here)
// MODE 1 (A): src_ids + u_env{unit,env} + pos_of_e (trig here)
// MODE 2 (C): src_ids + epos ONLY (8B/edge scattered; no r_ij read at all)
template<int F32, int MODE>
__device__ void pre_scatter_body(const void* __restrict__ r_ij, const int* __restrict__ nbrs,
        int is64, int* __restrict__ cursor, int* __restrict__ src_ids,
        float4* __restrict__ u_env, int* __restrict__ pos_of_e, float* __restrict__ gbuf,
        int* __restrict__ epos, int e, int nE, int nN) {
    const int d = clampi(get_dst(nbrs, e, is64), nN);
    const int j = clampi(get_src(nbrs, e, is64), nN);
    int pos = atomicAdd(&cursor[d], 1);
    pos = clampi(pos, nE);
    src_ids[pos] = j;

    if (MODE == 2) {
        epos[pos] = e;
        return;
    }

    const float rx = LD<F32>(r_ij, (size_t)3 * e + 0);
    const float ry = LD<F32>(r_ij, (size_t)3 * e + 1);
    const float rz = LD<F32>(r_ij, (size_t)3 * e + 2);
    const float d2   = rx * rx + ry * ry + rz * rz + 3e-15f;
    const float invd = rsqrtf(d2);
    const float dd   = d2 * invd;
    const float x  = dd * KSCALE;
    const float c1 = F32 ? cosf(x) : __cosf(x);
    const float env = (dd < CUTOFF_F) ? (0.5f * (c1 + 1.0f)) : 0.0f;
    u_env[pos] = make_float4(rx * invd, ry * invd, rz * invd, env);

    if (MODE == 1) {
        pos_of_e[e] = pos;
    } else {
        const float s1 = F32 ? sinf(x) : __sinf(x);
        const float scale = invd * env;
        const float tc = 2.0f * c1;
        float skm2 = 0.f, skm1 = s1;
        float* g = gbuf + (size_t)pos * NRBF;
        g[0] = s1 * scale;
        #pragma unroll
        for (int k = 1; k < NRBF; ++k) {
            const float sk = fmaf(tc, skm1, -skm2);
            g[k] = sk * scale;
            skm2 = skm1; skm1 = sk;
        }
    }
}

__global__ __launch_bounds__(256) void pre_scatter_kernel(const void* r_ij, const int* nbrs,
        const int* __restrict__ flags, int* cursor, int* src_ids, float4* u_env,
        int* pos_of_e, float* gbuf, int* epos, int nE, int nN, int mode) {
    int e = blockIdx.x * blockDim.x + threadIdx.x;
    if (e >= nE) return;
    const int F32 = flags[0], is64 = flags[1];
    if (mode == 2) {
        if (F32) pre_scatter_body<1,2>(r_ij, nbrs, is64, cursor, src_ids, u_env, pos_of_e, gbuf, epos, e, nE, nN);
        else     pre_scatter_body<0,2>(r_ij, nbrs, is64, cursor, src_ids, u_env, pos_of_e, gbuf, epos, e, nE, nN);
    } else if (mode == 1) {
        if (F32) pre_scatter_body<1,1>(r_ij, nbrs, is64, cursor, src_ids, u_env, pos_of_e, gbuf, epos, e, nE, nN);
        else     pre_scatter_body<0,1>(r_ij, nbrs, is64, cursor, src_ids, u_env, pos_of_e, gbuf, epos, e, nE, nN);
    } else {
        if (F32) pre_scatter_body<1,0>(r_ij, nbrs, is64, cursor, src_ids, u_env, pos_of_e, gbuf, epos, e, nE, nN);
        else     pre_scatter_body<0,0>(r_ij, nbrs, is64, cursor, src_ids, u_env, pos_of_e, gbuf, epos, e, nE, nN);
    }
}

// ---------- mode C: finalize u4 = {ux,uy,uz,binf}; coalesced over pos ----------
// Hoists the per-edge uniform math out of msg_c (it was replicated x128 lanes).
template<int F32>
__device__ void finalize_u4_body(const void* __restrict__ r_ij, const int* __restrict__ epos,
        float4* __restrict__ u4, int t, int nE) {
    const int e = clampi(epos[t], nE);
    const float rx = LD<F32>(r_ij, (size_t)3 * e + 0);
    const float ry = LD<F32>(r_ij, (size_t)3 * e + 1);
    const float rz = LD<F32>(r_ij, (size_t)3 * e + 2);
    const float d2   = rx * rx + ry * ry + rz * rz + 3e-15f;
    const float invd = rsqrtf(d2);
    const float dd   = d2 * invd;
    u4[t] = make_float4(rx * invd, ry * invd, rz * invd, dd * INV_H);
}

__global__ __launch_bounds__(256) void finalize_u4_kernel(const void* r_ij,
        const int* __restrict__ epos, float4* __restrict__ u4,
        const int* __restrict__ flags, int nE) {
    int t = blockIdx.x * blockDim.x + threadIdx.x;
    if (t >= nE) return;
    if (flags[0]) finalize_u4_body<1>(r_ij, epos, u4, t, nE);
    else          finalize_u4_body<0>(r_ij, epos, u4, t, nE);
}

// ---------- fused node MLP: phi = silu(s@W1+b1)@W2 + b2 ----------
// packed=1: rec[node][f][6] slots 0..2 = phi012, slots 3..5 = v_j (bf16) [pack_v fused]
template<int F32>
__device__ void gemm_body(const void* __restrict__ s_j, const void* __restrict__ v_j,
                          const void* __restrict__ W1,
                          const void* __restrict__ b1, const void* __restrict__ W2,
                          const void* __restrict__ b2v, bf16* __restrict__ phi, int nN,
                          int packed) {
    __shared__ float sl[8][FEAT];
    __shared__ float hl[8][FEAT];
    const int t = threadIdx.x;
    const int n0 = blockIdx.x * 8;
    const int fch  = t & 127;
    const int comp = t >> 7;

    if (packed) {
        #pragma unroll
        for (int n = 0; n < 8; ++n) {
            int row = n0 + n;
            if (row < nN) {
                const float vv = LD<F32>(v_j, ((size_t)row * FEAT + fch) * 3 + comp);
                phi[((size_t)row * FEAT + fch) * 6 + 3 + comp] = f2b(vv);
            }
        }
    }

    for (int idx = t; idx < 8 * FEAT; idx += 384) {
        int n = idx >> 7, k = idx & 127;
        int row = n0 + n;
        sl[n][k] = (row < nN) ? LD<F32>(s_j, (size_t)row * FEAT + k) : 0.f;
    }
    __syncthreads();
    for (int idx = t; idx < 8 * FEAT; idx += 384) {
        int n = idx >> 7, f = idx & 127;
        float a = 0.f;
        #pragma unroll 4
        for (int k = 0; k < FEAT; ++k) a = fmaf(sl[n][k], LD<F32>(W1, (size_t)k * FEAT + f), a);
        a += LD<F32>(b1, f);
        float sg = F32 ? (1.0f / (1.0f + expf(-a))) : (1.0f / (1.0f + __expf(-a)));
        hl[n][f] = a * sg;
    }
    __syncthreads();
    float acc[8] = {};
    #pragma unroll 4
    for (int k = 0; k < FEAT; ++k) {
        const float w = LD<F32>(W2, (size_t)k * 384 + t);
        #pragma unroll
        for (int n = 0; n < 8; ++n) acc[n] = fmaf(hl[n][k], w, acc[n]);
    }
    const float bb = LD<F32>(b2v, t);
    #pragma unroll
    for (int n = 0; n < 8; ++n) {
        int row = n0 + n;
        if (row < nN) {
            if (packed) phi[((size_t)row * FEAT + fch) * 6 + comp] = f2b(acc[n] + bb);
            else        phi[(size_t)row * 384 + t] = f2b(acc[n] + bb);
        }
    }
}

__global__ __launch_bounds__(384) void gemm_node_kernel(const void* s_j, const void* v_j,
        const void* W1, const void* b1, const void* W2, const void* b2v, bf16* phi,
        const int* __restrict__ flags, int nN, int packed) {
    if (flags[0]) gemm_body<1>(s_j, v_j, W1, b1, W2, b2v, phi, nN, packed);
    else          gemm_body<0>(s_j, v_j, W1, b1, W2, b2v, phi, nN, packed);
}

// ---------- mode A: per-edge w_s GEMM ----------
template<int F32>
__device__ void pre_ws_body(const void* __restrict__ r_ij, const float* __restrict__ WdT,
        const int* __restrict__ pos_of_e, bf16* __restrict__ ws_w, int e) {
    const float rx = LD<F32>(r_ij, (size_t)3 * e + 0);
    const float ry = LD<F32>(r_ij, (size_t)3 * e + 1);
    const float rz = LD<F32>(r_ij, (size_t)3 * e + 2);
    const float d2   = rx * rx + ry * ry + rz * rz + 3e-15f;
    const float invd = rsqrtf(d2);
    const float dd   = d2 * invd;
    const float x  = dd * KSCALE;
    const float s1 = F32 ? sinf(x) : __sinf(x);
    const float c1 = F32 ? cosf(x) : __cosf(x);
    const float env = (dd < CUTOFF_F) ? (0.5f * (c1 + 1.0f)) : 0.0f;
    const float scale = invd * env;
    float gk[NRBF];
    const float tc = 2.0f * c1;
    float skm2 = 0.f, skm1 = s1;
    gk[0] = s1 * scale;
    #pragma unroll
    for (int k = 1; k < NRBF; ++k) {
        const float sk = fmaf(tc, skm1, -skm2);
        gk[k] = sk * scale;
        skm2 = skm1; skm1 = sk;
    }
    const int pos = pos_of_e[e];
    bf16* dst = ws_w + (size_t)pos * 384;
    for (int c0 = 0; c0 < 384; c0 += 4) {
        float r[4];
        #pragma unroll
        for (int u = 0; u < 4; ++u) {
            const float* w = WdT + (size_t)(c0 + u) * 24;
            float acc = w[20] * env;
            #pragma unroll
            for (int k = 0; k < NRBF; ++k) acc = fmaf(gk[k], w[k], acc);
            r[u] = acc;
        }
        union { bf16 b[4]; uint2 u2; } pk;
        pk.b[0] = f2b(r[0]); pk.b[1] = f2b(r[1]); pk.b[2] = f2b(r[2]); pk.b[3] = f2b(r[3]);
        *(uint2*)(dst + c0) = pk.u2;
    }
}

__global__ __launch_bounds__(256) void pre_ws_kernel(const void* r_ij,
        const float* __restrict__ WdT, const int* __restrict__ pos_of_e,
        bf16* __restrict__ ws_w, const int* __restrict__ flags, int nE) {
    int e = blockIdx.x * blockDim.x + threadIdx.x;
    if (e >= nE) return;
    if (flags[0]) pre_ws_body<1>(r_ij, WdT, pos_of_e, ws_w, e);
    else          pre_ws_body<0>(r_ij, WdT, pos_of_e, ws_w, e);
}

// ---------- mode A message: pure gather-accumulate ----------
template<int F32>
__device__ void msg_a_body(const bf16* __restrict__ ws_w, const bf16* __restrict__ phi,
        const void* __restrict__ v_j, const int* __restrict__ src_ids,
        const float4* __restrict__ u_env, const int* __restrict__ offsets,
        void* __restrict__ out, int nE, int nN) {
    const int i = blockIdx.x;
    const int f = threadIdx.x;
    int start = offsets[i];
    int end   = offsets[i + 1];
    if (start < 0) start = 0;
    if (end > nE) end = nE;

    float ds = 0.f, dv0 = 0.f, dv1 = 0.f, dv2 = 0.f;

    #pragma unroll 2
    for (int p = start; p < end; ++p) {
        const int j = src_ids[p];
        const float4 ue = u_env[p];
        const bf16* wr = ws_w + (size_t)p * 384;
        const float w0 = b2f(wr[f]);
        const float w1 = b2f(wr[FEAT + f]);
        const float w2 = b2f(wr[2 * FEAT + f]);
        const bf16* ph = phi + (size_t)j * 384;
        const float p0 = b2f(ph[f]);
        const float p1 = b2f(ph[FEAT + f]);
        const float p2 = b2f(ph[2 * FEAT + f]);
        const float vx = LD<F32>(v_j, ((size_t)j * FEAT + f) * 3 + 0);
        const float vy = LD<F32>(v_j, ((size_t)j * FEAT + f) * 3 + 1);
        const float vz = LD<F32>(v_j, ((size_t)j * FEAT + f) * 3 + 2);
        const float i0 = w0 * p0;
        const float i1 = w1 * p1;
        const float i2 = w2 * p2;
        ds += i1;
        dv0 = fmaf(i2, ue.x, fmaf(i0, vx, dv0));
        dv1 = fmaf(i2, ue.y, fmaf(i0, vy, dv1));
        dv2 = fmaf(i2, ue.z, fmaf(i0, vz, dv2));
    }

    ST<F32>(out, (size_t)i * FEAT + f, ds);
    const size_t ob = (size_t)nN * FEAT + ((size_t)i * FEAT + f) * 3;
    ST<F32>(out, ob + 0, dv0);
    ST<F32>(out, ob + 1, dv1);
    ST<F32>(out, ob + 2, dv2);
}

__global__ __launch_bounds__(128) void msg_a_kernel(const bf16* ws_w, const bf16* phi,
        const void* v_j, const int* src_ids, const float4* u_env, const int* offsets,
        const int* __restrict__ flags, void* out, int nE, int nN) {
    if (flags[0]) msg_a_body<1>(ws_w, phi, v_j, src_ids, u_env, offsets, out, nE, nN);
    else          msg_a_body<0>(ws_w, phi, v_j, src_ids, u_env, offsets, out, nE, nN);
}

// ---------- mode C message: table-lerp w_s + 12B packed gather; u4 precomputed ----------
// Per edge per thread: uniform 16B u4 + 6x 2B table loads + 12B rec gather + ~29 VALU.
template<int F32>
__device__ void msg_c_body(const unsigned short* __restrict__ tab, const bf16* __restrict__ rec,
        const float4* __restrict__ u4, const int* __restrict__ src_ids,
        const int* __restrict__ offsets, void* __restrict__ out, int nE, int nN) {
    const int i = blockIdx.x;
    const int f = threadIdx.x;
    int start = offsets[i];
    int end   = offsets[i + 1];
    if (start < 0) start = 0;
    if (end > nE) end = nE;

    float ds = 0.f, dv0 = 0.f, dv1 = 0.f, dv2 = 0.f;

    for (int p = start; p < end; ++p) {
        const int j = src_ids[p];
        const float4 uu = u4[p];           // uniform -> s_load
        const float binf = uu.w;
        int bin = (int)binf;
        if (bin > NB - 2) bin = NB - 2;
        const float fr = binf - (float)bin;
        const float m = (binf < (float)(NB - 1)) ? 1.0f : 0.0f;   // d < CUTOFF

        const unsigned short* T = tab + (size_t)bin * 384;
        const float t00 = us2f(T[f]);
        const float t01 = us2f(T[384 + f]);
        const float t10 = us2f(T[FEAT + f]);
        const float t11 = us2f(T[384 + FEAT + f]);
        const float t20 = us2f(T[2 * FEAT + f]);
        const float t21 = us2f(T[384 + 2 * FEAT + f]);
        const float w0 = fmaf(t01 - t00, fr, t00) * m;
        const float w1 = fmaf(t11 - t10, fr, t10) * m;
        const float w2 = fmaf(t21 - t20, fr, t20) * m;

        // 12B gather: {phi0,phi1,phi2,vx,vy,vz} bf16, 4B-aligned
        const unsigned* rp = (const unsigned*)(rec + ((size_t)j * FEAT + f) * 6);
        const unsigned ra = rp[0];
        const unsigned rb = rp[1];
        const unsigned rc = rp[2];
        const float p0 = __uint_as_float(ra << 16);
        const float p1 = __uint_as_float(ra & 0xffff0000u);
        const float p2 = __uint_as_float(rb << 16);
        const float vx = __uint_as_float(rb & 0xffff0000u);
        const float vy = __uint_as_float(rc << 16);
        const float vz = __uint_as_float(rc & 0xffff0000u);

        const float i0 = w0 * p0;
        const float i1 = w1 * p1;
        const float i2 = w2 * p2;
        ds += i1;
        dv0 = fmaf(i2, uu.x, fmaf(i0, vx, dv0));
        dv1 = fmaf(i2, uu.y, fmaf(i0, vy, dv1));
        dv2 = fmaf(i2, uu.z, fmaf(i0, vz, dv2));
    }

    ST<F32>(out, (size_t)i * FEAT + f, ds);
    const size_t ob = (size_t)nN * FEAT + ((size_t)i * FEAT + f) * 3;
    ST<F32>(out, ob + 0, dv0);
    ST<F32>(out, ob + 1, dv1);
    ST<F32>(out, ob + 2, dv2);
}

__global__ __launch_bounds__(128) void msg_c_kernel(const unsigned short* tab, const bf16* rec,
        const float4* u4, const int* src_ids, const int* offsets,
        const int* __restrict__ flags, void* out, int nE, int nN) {
    if (flags[0]) msg_c_body<1>(tab, rec, u4, src_ids, offsets, out, nE, nN);
    else          msg_c_body<0>(tab, rec, u4, src_ids, offsets, out, nE, nN);
}

// ---------- mode B message (exact R0 baseline fallback) ----------
template<int F32>
__device__ void msg_b_body(const void* __restrict__ v_j, const void* __restrict__ Wd,
        const void* __restrict__ bd, const bf16* __restrict__ phi,
        const float* __restrict__ gbuf, const int* __restrict__ src_ids,
        const float4* __restrict__ u_env, const int* __restrict__ offsets,
        void* __restrict__ out, int nE, int nN) {
    const int i = blockIdx.x;
    const int f = threadIdx.x;

    float wd0[NRBF], wd1[NRBF], wd2[NRBF];
    #pragma unroll
    for (int k = 0; k < NRBF; ++k) {
        wd0[k] = LD<F32>(Wd, (size_t)k * 384 + f);
        wd1[k] = LD<F32>(Wd, (size_t)k * 384 + FEAT + f);
        wd2[k] = LD<F32>(Wd, (size_t)k * 384 + 2 * FEAT + f);
    }
    const float bd0 = LD<F32>(bd, f);
    const float bd1 = LD<F32>(bd, FEAT + f);
    const float bd2 = LD<F32>(bd, 2 * FEAT + f);

    int start = offsets[i];
    int end   = offsets[i + 1];
    if (start < 0) start = 0;
    if (end > nE) end = nE;

    float ds = 0.f, dv0 = 0.f, dv1 = 0.f, dv2 = 0.f;

    for (int p = start; p < end; ++p) {
        const int j = src_ids[p];
        const float4 ue = u_env[p];
        const float* g = gbuf + (size_t)p * NRBF;
        float t0 = 0.f, t1 = 0.f, t2 = 0.f;
        #pragma unroll
        for (int k = 0; k < NRBF; ++k) {
            const float gk = g[k];
            t0 = fmaf(gk, wd0[k], t0);
            t1 = fmaf(gk, wd1[k], t1);
            t2 = fmaf(gk, wd2[k], t2);
        }
        const float w0 = fmaf(bd0, ue.w, t0);
        const float w1 = fmaf(bd1, ue.w, t1);
        const float w2 = fmaf(bd2, ue.w, t2);

        const bf16* ph = phi + (size_t)j * 384;
        const float p0 = b2f(ph[f]);
        const float p1 = b2f(ph[FEAT + f]);
        const float p2 = b2f(ph[2 * FEAT + f]);
        const float vx = LD<F32>(v_j, ((size_t)j * FEAT + f) * 3 + 0);
        const float vy = LD<F32>(v_j, ((size_t)j * FEAT + f) * 3 + 1);
        const float vz = LD<F32>(v_j, ((size_t)j * FEAT + f) * 3 + 2);

        const float i0 = w0 * p0;
        const float i1 = w1 * p1;
        const float i2 = w2 * p2;
        ds += i1;
        dv0 = fmaf(i2, ue.x, fmaf(i0, vx, dv0));
        dv1 = fmaf(i2, ue.y, fmaf(i0, vy, dv1));
        dv2 = fmaf(i2, ue.z, fmaf(i0, vz, dv2));
    }

    ST<F32>(out, (size_t)i * FEAT + f, ds);
    const size_t ob = (size_t)nN * FEAT + ((size_t)i * FEAT + f) * 3;
    ST<F32>(out, ob + 0, dv0);
    ST<F32>(out, ob + 1, dv1);
    ST<F32>(out, ob + 2, dv2);
}

__global__ __launch_bounds__(128) void msg_b_kernel(const void* v_j, const void* Wd,
        const void* bd, const bf16* phi, const float* gbuf, const int* src_ids,
        const float4* u_env, const int* offsets, const int* __restrict__ flags,
        void* out, int nE, int nN) {
    if (flags[0]) msg_b_body<1>(v_j, Wd, bd, phi, gbuf, src_ids, u_env, offsets, out, nE, nN);
    else          msg_b_body<0>(v_j, Wd, bd, phi, gbuf, src_ids, u_env, offsets, out, nE, nN);
}

extern "C" void kernel_launch(void* const* d_in, const int* in_sizes, int n_in,
                              void* d_out, int out_size, void* d_ws, size_t ws_size,
                              hipStream_t stream) {
    const void* s_j  = d_in[0];
    const void* v_j  = d_in[1];
    const void* r_ij = d_in[2];
    const int*  nbrs = (const int*)d_in[3];
    const void* W1   = d_in[4];
    const void* b1   = d_in[5];
    const void* W2   = d_in[6];
    const void* b2   = d_in[7];
    const void* Wd   = d_in[8];
    const void* bd   = d_in[9];

    const int nN = out_size / (4 * FEAT);   // 20000
    const int nE = in_sizes[2] / 3;         // 640000

    char* ws = (char*)d_ws;
    size_t off = 0;
    auto alloc = [&](size_t bytes) -> void* {
        void* p = ws + off;
        off = (off + bytes + 255) & ~(size_t)255;
        return p;
    };
    int*    flags    = (int*)alloc(16);
    int*    counts   = (int*)alloc((size_t)nN * 4);
    int*    offsets  = (int*)alloc(((size_t)nN + 1) * 4);
    int*    cursor   = (int*)alloc((size_t)nN * 4);
    int*    src_ids  = (int*)alloc((size_t)nE * 4);
    float4* u_env    = (float4*)alloc((size_t)nE * 16);
    int*    epos     = (int*)alloc((size_t)nE * 4);
    float*  WdT      = (float*)alloc((size_t)384 * 24 * 4);
    const size_t base = off;

    // mode A layout: pos_of_e | phi | ws_w
    size_t offA = base;
    int*  pos_of_e = (int*)(ws + offA);  offA += ((size_t)nE * 4 + 255) & ~(size_t)255;
    bf16* phiA     = (bf16*)(ws + offA); offA += ((size_t)nN * 384 * 2 + 255) & ~(size_t)255;
    bf16* ws_w     = (bf16*)(ws + offA); offA += (size_t)nE * 384 * 2;
    // mode C layout: rec (12B per (node,f)) | tab
    size_t offC = base;
    bf16* rec = (bf16*)(ws + offC);      offC += ((size_t)nN * FEAT * 6 * 2 + 255) & ~(size_t)255;
    bf16* tab = (bf16*)(ws + offC);      offC += (size_t)NB * 384 * 2;
    // mode B layout: gbuf | phi
    size_t offB = base;
    float* gbufB = (float*)(ws + offB);  offB += ((size_t)nE * NRBF * 4 + 255) & ~(size_t)255;
    bf16*  phiB  = (bf16*)(ws + offB);   offB += (size_t)nN * 384 * 2;

    const int modeA = (ws_size >= offA) ? 1 : 0;
    const int modeC = (!modeA && ws_size >= offC) ? 1 : 0;

    init_kernel<<<(nN + 255) / 256, 256, 0, stream>>>(s_j, nbrs, nE, flags, counts, nN);
    hist_kernel<<<(nE + 255) / 256, 256, 0, stream>>>(nbrs, flags, counts, nE, nN);
    scan_kernel<<<1, 1024, 0, stream>>>(counts, offsets, cursor, nN);
    prep_kernel<<<1, 384, 0, stream>>>(Wd, bd, WdT, flags);

    const int psMode = modeA ? 1 : (modeC ? 2 : 0);
    pre_scatter_kernel<<<(nE + 255) / 256, 256, 0, stream>>>(
        r_ij, nbrs, flags, cursor, src_ids, u_env, pos_of_e, gbufB, epos, nE, nN, psMode);

    if (modeA) {
        gemm_node_kernel<<<(nN + 7) / 8, 384, 0, stream>>>(s_j, v_j, W1, b1, W2, b2, phiA, flags, nN, 0);
        pre_ws_kernel<<<(nE + 255) / 256, 256, 0, stream>>>(r_ij, WdT, pos_of_e, ws_w, flags, nE);
        msg_a_kernel<<<nN, 128, 0, stream>>>(ws_w, phiA, v_j, src_ids, u_env, offsets,
                                             flags, d_out, nE, nN);
    } else if (modeC) {
        finalize_u4_kernel<<<(nE + 255) / 256, 256, 0, stream>>>(r_ij, epos, u_env, flags, nE);
        build_table_kernel<<<NB, 384, 0, stream>>>(WdT, tab);
        gemm_node_kernel<<<(nN + 7) / 8, 384, 0, stream>>>(s_j, v_j, W1, b1, W2, b2, rec, flags, nN, 1);
        msg_c_kernel<<<nN, 128, 0, stream>>>((const unsigned short*)tab, rec, u_env, src_ids,
                                             offsets, flags, d_out, nE, nN);
    } else {
        gemm_node_kernel<<<(nN + 7) / 8, 384, 0, stream>>>(s_j, v_j, W1, b1, W2, b2, phiB, flags, nN, 0);
        msg_b_kernel<<<nN, 128, 0, stream>>>(v_j, Wd, bd, phiB, gbufB, src_ids, u_env,
                                             offsets, flags, d_out, nE, nN);
    }
}

// Round 11
// 489.842 us; speedup vs baseline: 1.1427x; 1.0221x over previous
//
#include <hip/hip_runtime.h>
#include <hip/hip_bf16.h>
#include <math.h>

typedef __hip_bfloat16 bf16;

#define FEAT 128
#define NRBF 20
#define CUTOFF_F 5.0f
#define KSCALE 0.62831853071795864769f  // pi / 5
#define NB 4096
#define INV_H 819.0f                    // (NB-1)/CUTOFF
#define H_STEP 0.001221001221001221f    // CUTOFF/(NB-1)

__device__ __forceinline__ float b2f(bf16 x) { return __bfloat162float(x); }
__device__ __forceinline__ bf16 f2b(float x) { return __float2bfloat16(x); }
__device__ __forceinline__ float us2f(unsigned short u) {
    return __uint_as_float(((unsigned)u) << 16);
}

template<int F32>
__device__ __forceinline__ float LD(const void* p, size_t i) {
    if (F32) return ((const float*)p)[i];
    return b2f(((const bf16*)p)[i]);
}
template<int F32>
__device__ __forceinline__ void ST(void* p, size_t i, float v) {
    if (F32) ((float*)p)[i] = v;
    else ((bf16*)p)[i] = f2b(v);
}

__device__ __forceinline__ int get_dst(const int* nb, int e, int is64) {
    return is64 ? nb[4 * e] : nb[2 * e];
}
__device__ __forceinline__ int get_src(const int* nb, int e, int is64) {
    return is64 ? nb[4 * e + 2] : nb[2 * e + 1];
}
__device__ __forceinline__ int clampi(int v, int n) {
    return v < 0 ? 0 : (v >= n ? n - 1 : v);
}

// ---------- init: zero counts + sniff dtypes ----------
__global__ void init_kernel(const void* __restrict__ s_ptr, const int* __restrict__ nbrs32,
                            int nE, int* __restrict__ flags, int* __restrict__ counts, int nN) {
    int t = blockIdx.x * blockDim.x + threadIdx.x;
    if (t < nN) counts[t] = 0;
    if (t == 0) {
        const unsigned* u = (const unsigned*)s_ptr;
        int hits = 0;
        for (int i = 0; i < 64; ++i) {
            unsigned ef = (u[i] >> 7) & 0xFF;
            hits += (ef >= 110 && ef <= 135) ? 1 : 0;
        }
        flags[0] = (hits < 32) ? 1 : 0;   // 1 => f32 inputs
        int lim = 2 * nE; if (lim > 128) lim = 128;
        int allz = 1;
        for (int i = 1; i < lim; i += 2) allz &= (nbrs32[i] == 0);
        flags[1] = allz;                   // 1 => int64 nbrs
    }
}

// ---------- CSR build ----------
__global__ void hist_kernel(const int* __restrict__ nbrs, const int* __restrict__ flags,
                            int* __restrict__ counts, int nE, int nN) {
    int e = blockIdx.x * blockDim.x + threadIdx.x;
    if (e < nE) {
        int d = clampi(get_dst(nbrs, e, flags[1]), nN);
        atomicAdd(&counts[d], 1);
    }
}

__global__ __launch_bounds__(1024) void scan_kernel(const int* __restrict__ counts,
        int* __restrict__ offsets, int* __restrict__ cursor, int nN) {
    __shared__ int part[1024];
    const int t = threadIdx.x;
    const int chunk = (nN + 1023) / 1024;
    const int base = t * chunk;
    int local[32];
    int sum = 0;
    for (int c = 0; c < chunk && c < 32; ++c) {
        int idx = base + c;
        int v = (idx < nN) ? counts[idx] : 0;
        local[c] = v;
        sum += v;
    }
    part[t] = sum;
    __syncthreads();
    for (int off = 1; off < 1024; off <<= 1) {
        int add = (t >= off) ? part[t - off] : 0;
        __syncthreads();
        part[t] += add;
        __syncthreads();
    }
    int run = part[t] - sum;
    for (int c = 0; c < chunk && c < 32; ++c) {
        int idx = base + c;
        if (idx < nN) { offsets[idx] = run; cursor[idx] = run; run += local[c]; }
    }
    if (t == 1023) offsets[nN] = part[1023];
}

// ---------- prep (mode A only): WdT[c][0..19] = Wd[k][c], WdT[c][20] = bd[c] ----------
__global__ __launch_bounds__(384) void prep_kernel(const void* __restrict__ Wd,
        const void* __restrict__ bd, float* __restrict__ WdT, const int* __restrict__ flags) {
    const int c = threadIdx.x;
    const int F32 = flags[0];
    if (F32) {
        for (int k = 0; k < NRBF; ++k) WdT[c * 24 + k] = ((const float*)Wd)[k * 384 + c];
        WdT[c * 24 + 20] = ((const float*)bd)[c];
    } else {
        for (int k = 0; k < NRBF; ++k) WdT[c * 24 + k] = b2f(((const bf16*)Wd)[k * 384 + c]);
        WdT[c * 24 + 20] = b2f(((const bf16*)bd)[c]);
    }
    WdT[c * 24 + 21] = 0.f; WdT[c * 24 + 22] = 0.f; WdT[c * 24 + 23] = 0.f;
}

// ---------- mode C: w_s lookup table, direct from Wd/bd ----------
// tab[b][c] = (rbf(d_b)@Wd + bd)[c] * env(d_b),  d_b = b*H_STEP, bf16
__global__ __launch_bounds__(384) void build_table_kernel(const void* __restrict__ Wd,
        const void* __restrict__ bd, bf16* __restrict__ tab, const int* __restrict__ flags) {
    const int b = blockIdx.x;
    const int c = threadIdx.x;
    const int F32 = flags[0];
    const float d = fmaxf(b * H_STEP, 1e-7f);
    const float x = d * KSCALE;
    const float s1 = sinf(x);
    const float c1 = cosf(x);
    const float env = (d < CUTOFF_F) ? (0.5f * (c1 + 1.0f)) : 0.0f;
    const float invd = 1.0f / d;
    float g[NRBF];
    const float tc = 2.0f * c1;
    float skm2 = 0.f, skm1 = s1;
    g[0] = s1 * invd;
    #pragma unroll
    for (int k = 1; k < NRBF; ++k) {
        const float sk = fmaf(tc, skm1, -skm2);
        g[k] = sk * invd;
        skm2 = skm1; skm1 = sk;
    }
    float acc = F32 ? ((const float*)bd)[c] : b2f(((const bf16*)bd)[c]);
    #pragma unroll
    for (int k = 0; k < NRBF; ++k) {
        const float w = F32 ? ((const float*)Wd)[(size_t)k * 384 + c]
                            : b2f(((const bf16*)Wd)[(size_t)k * 384 + c]);
        acc = fmaf(g[k], w, acc);
    }
    tab[(size_t)b * 384 + c] = f2b(acc * env);
}

// ---------- scatter + per-position side records ----------
// MODE 0 (B): src_ids + u_env{unit,env} + gbuf (trig here)
// MODE 1 (A): src_ids + u_env{unit,env} + pos_of_e (trig here)
// MODE 2 (C): src_ids + u4{unit,binf} fused (rsqrt only, no trig; 20B/edge scattered)
template<int F32, int MODE>
__device__ void pre_scatter_body(const void* __restrict__ r_ij, const int* __restrict__ nbrs,
        int is64, int* __restrict__ cursor, int* __restrict__ src_ids,
        float4* __restrict__ u_env, int* __restrict__ pos_of_e, float* __restrict__ gbuf,
        int e, int nE, int nN) {
    const int d = clampi(get_dst(nbrs, e, is64), nN);
    const int j = clampi(get_src(nbrs, e, is64), nN);
    int pos = atomicAdd(&cursor[d], 1);
    pos = clampi(pos, nE);
    src_ids[pos] = j;

    const float rx = LD<F32>(r_ij, (size_t)3 * e + 0);
    const float ry = LD<F32>(r_ij, (size_t)3 * e + 1);
    const float rz = LD<F32>(r_ij, (size_t)3 * e + 2);
    const float d2   = rx * rx + ry * ry + rz * rz + 3e-15f;
    const float invd = rsqrtf(d2);
    const float dd   = d2 * invd;

    if (MODE == 2) {
        u_env[pos] = make_float4(rx * invd, ry * invd, rz * invd, dd * INV_H);
        return;
    }

    const float x  = dd * KSCALE;
    const float c1 = F32 ? cosf(x) : __cosf(x);
    const float env = (dd < CUTOFF_F) ? (0.5f * (c1 + 1.0f)) : 0.0f;
    u_env[pos] = make_float4(rx * invd, ry * invd, rz * invd, env);

    if (MODE == 1) {
        pos_of_e[e] = pos;
    } else {
        const float s1 = F32 ? sinf(x) : __sinf(x);
        const float scale = invd * env;
        const float tc = 2.0f * c1;
        float skm2 = 0.f, skm1 = s1;
        float* g = gbuf + (size_t)pos * NRBF;
        g[0] = s1 * scale;
        #pragma unroll
        for (int k = 1; k < NRBF; ++k) {
            const float sk = fmaf(tc, skm1, -skm2);
            g[k] = sk * scale;
            skm2 = skm1; skm1 = sk;
        }
    }
}

__global__ __launch_bounds__(256) void pre_scatter_kernel(const void* r_ij, const int* nbrs,
        const int* __restrict__ flags, int* cursor, int* src_ids, float4* u_env,
        int* pos_of_e, float* gbuf, int nE, int nN, int mode) {
    int e = blockIdx.x * blockDim.x + threadIdx.x;
    if (e >= nE) return;
    const int F32 = flags[0], is64 = flags[1];
    if (mode == 2) {
        if (F32) pre_scatter_body<1,2>(r_ij, nbrs, is64, cursor, src_ids, u_env, pos_of_e, gbuf, e, nE, nN);
        else     pre_scatter_body<0,2>(r_ij, nbrs, is64, cursor, src_ids, u_env, pos_of_e, gbuf, e, nE, nN);
    } else if (mode == 1) {
        if (F32) pre_scatter_body<1,1>(r_ij, nbrs, is64, cursor, src_ids, u_env, pos_of_e, gbuf, e, nE, nN);
        else     pre_scatter_body<0,1>(r_ij, nbrs, is64, cursor, src_ids, u_env, pos_of_e, gbuf, e, nE, nN);
    } else {
        if (F32) pre_scatter_body<1,0>(r_ij, nbrs, is64, cursor, src_ids, u_env, pos_of_e, gbuf, e, nE, nN);
        else     pre_scatter_body<0,0>(r_ij, nbrs, is64, cursor, src_ids, u_env, pos_of_e, gbuf, e, nE, nN);
    }
}

// ---------- fused node MLP: phi = silu(s@W1+b1)@W2 + b2 ----------
// R11: W1 stage k-split 3 ways (thread=(f,seg)); each W1 element loaded ONCE per
// block (64KB vs 512KB L2 traffic). Partials reduced via 12KB LDS.
// packed=1: rec[node][f][6] slots 0..2 = phi012, slots 3..5 = v_j (bf16)
template<int F32>
__device__ void gemm_body(const void* __restrict__ s_j, const void* __restrict__ v_j,
                          const void* __restrict__ W1,
                          const void* __restrict__ b1, const void* __restrict__ W2,
                          const void* __restrict__ b2v, bf16* __restrict__ phi, int nN,
                          int packed) {
    __shared__ float sl[8][FEAT];
    __shared__ float hl[8][FEAT];
    __shared__ float ps[3][8][FEAT];
    const int t = threadIdx.x;
    const int n0 = blockIdx.x * 8;
    const int fch = t & 127;
    const int seg = t >> 7;        // 0..2

    if (packed) {
        #pragma unroll
        for (int n = 0; n < 8; ++n) {
            int row = n0 + n;
            if (row < nN) {
                const float vv = LD<F32>(v_j, ((size_t)row * FEAT + fch) * 3 + seg);
                phi[((size_t)row * FEAT + fch) * 6 + 3 + seg] = f2b(vv);
            }
        }
    }

    for (int idx = t; idx < 8 * FEAT; idx += 384) {
        int n = idx >> 7, k = idx & 127;
        int row = n0 + n;
        sl[n][k] = (row < nN) ? LD<F32>(s_j, (size_t)row * FEAT + k) : 0.f;
    }
    __syncthreads();

    // W1 partial dot over this seg's k-range
    {
        const int k0 = seg * 43;
        const int k1 = (seg == 2) ? FEAT : k0 + 43;
        float part[8] = {};
        for (int k = k0; k < k1; ++k) {
            const float w = LD<F32>(W1, (size_t)k * FEAT + fch);
            #pragma unroll
            for (int n = 0; n < 8; ++n) part[n] = fmaf(sl[n][k], w, part[n]);
        }
        #pragma unroll
        for (int n = 0; n < 8; ++n) ps[seg][n][fch] = part[n];
    }
    __syncthreads();

    for (int idx = t; idx < 8 * FEAT; idx += 384) {
        int n = idx >> 7, f = idx & 127;
        float a = ps[0][n][f] + ps[1][n][f] + ps[2][n][f] + LD<F32>(b1, f);
        float sg = F32 ? (1.0f / (1.0f + expf(-a))) : (1.0f / (1.0f + __expf(-a)));
        hl[n][f] = a * sg;
    }
    __syncthreads();

    float acc[8] = {};
    #pragma unroll 4
    for (int k = 0; k < FEAT; ++k) {
        const float w = LD<F32>(W2, (size_t)k * 384 + t);
        #pragma unroll
        for (int n = 0; n < 8; ++n) acc[n] = fmaf(hl[n][k], w, acc[n]);
    }
    const float bb = LD<F32>(b2v, t);
    #pragma unroll
    for (int n = 0; n < 8; ++n) {
        int row = n0 + n;
        if (row < nN) {
            if (packed) phi[((size_t)row * FEAT + fch) * 6 + seg] = f2b(acc[n] + bb);
            else        phi[(size_t)row * 384 + t] = f2b(acc[n] + bb);
        }
    }
}

__global__ __launch_bounds__(384) void gemm_node_kernel(const void* s_j, const void* v_j,
        const void* W1, const void* b1, const void* W2, const void* b2v, bf16* phi,
        const int* __restrict__ flags, int nN, int packed) {
    if (flags[0]) gemm_body<1>(s_j, v_j, W1, b1, W2, b2v, phi, nN, packed);
    else          gemm_body<0>(s_j, v_j, W1, b1, W2, b2v, phi, nN, packed);
}

// ---------- mode A: per-edge w_s GEMM ----------
template<int F32>
__device__ void pre_ws_body(const void* __restrict__ r_ij, const float* __restrict__ WdT,
        const int* __restrict__ pos_of_e, bf16* __restrict__ ws_w, int e) {
    const float rx = LD<F32>(r_ij, (size_t)3 * e + 0);
    const float ry = LD<F32>(r_ij, (size_t)3 * e + 1);
    const float rz = LD<F32>(r_ij, (size_t)3 * e + 2);
    const float d2   = rx * rx + ry * ry + rz * rz + 3e-15f;
    const float invd = rsqrtf(d2);
    const float dd   = d2 * invd;
    const float x  = dd * KSCALE;
    const float s1 = F32 ? sinf(x) : __sinf(x);
    const float c1 = F32 ? cosf(x) : __cosf(x);
    const float env = (dd < CUTOFF_F) ? (0.5f * (c1 + 1.0f)) : 0.0f;
    const float scale = invd * env;
    float gk[NRBF];
    const float tc = 2.0f * c1;
    float skm2 = 0.f, skm1 = s1;
    gk[0] = s1 * scale;
    #pragma unroll
    for (int k = 1; k < NRBF; ++k) {
        const float sk = fmaf(tc, skm1, -skm2);
        gk[k] = sk * scale;
        skm2 = skm1; skm1 = sk;
    }
    const int pos = pos_of_e[e];
    bf16* dst = ws_w + (size_t)pos * 384;
    for (int c0 = 0; c0 < 384; c0 += 4) {
        float r[4];
        #pragma unroll
        for (int u = 0; u < 4; ++u) {
            const float* w = WdT + (size_t)(c0 + u) * 24;
            float acc = w[20] * env;
            #pragma unroll
            for (int k = 0; k < NRBF; ++k) acc = fmaf(gk[k], w[k], acc);
            r[u] = acc;
        }
        union { bf16 b[4]; uint2 u2; } pk;
        pk.b[0] = f2b(r[0]); pk.b[1] = f2b(r[1]); pk.b[2] = f2b(r[2]); pk.b[3] = f2b(r[3]);
        *(uint2*)(dst + c0) = pk.u2;
    }
}

__global__ __launch_bounds__(256) void pre_ws_kernel(const void* r_ij,
        const float* __restrict__ WdT, const int* __restrict__ pos_of_e,
        bf16* __restrict__ ws_w, const int* __restrict__ flags, int nE) {
    int e = blockIdx.x * blockDim.x + threadIdx.x;
    if (e >= nE) return;
    if (flags[0]) pre_ws_body<1>(r_ij, WdT, pos_of_e, ws_w, e);
    else          pre_ws_body<0>(r_ij, WdT, pos_of_e, ws_w, e);
}

// ---------- mode A message: pure gather-accumulate ----------
template<int F32>
__device__ void msg_a_body(const bf16* __restrict__ ws_w, const bf16* __restrict__ phi,
        const void* __restrict__ v_j, const int* __restrict__ src_ids,
        const float4* __restrict__ u_env, const int* __restrict__ offsets,
        void* __restrict__ out, int nE, int nN) {
    const int i = blockIdx.x;
    const int f = threadIdx.x;
    int start = offsets[i];
    int end   = offsets[i + 1];
    if (start < 0) start = 0;
    if (end > nE) end = nE;

    float ds = 0.f, dv0 = 0.f, dv1 = 0.f, dv2 = 0.f;

    #pragma unroll 2
    for (int p = start; p < end; ++p) {
        const int j = src_ids[p];
        const float4 ue = u_env[p];
        const bf16* wr = ws_w + (size_t)p * 384;
        const float w0 = b2f(wr[f]);
        const float w1 = b2f(wr[FEAT + f]);
        const float w2 = b2f(wr[2 * FEAT + f]);
        const bf16* ph = phi + (size_t)j * 384;
        const float p0 = b2f(ph[f]);
        const float p1 = b2f(ph[FEAT + f]);
        const float p2 = b2f(ph[2 * FEAT + f]);
        const float vx = LD<F32>(v_j, ((size_t)j * FEAT + f) * 3 + 0);
        const float vy = LD<F32>(v_j, ((size_t)j * FEAT + f) * 3 + 1);
        const float vz = LD<F32>(v_j, ((size_t)j * FEAT + f) * 3 + 2);
        const float i0 = w0 * p0;
        const float i1 = w1 * p1;
        const float i2 = w2 * p2;
        ds += i1;
        dv0 = fmaf(i2, ue.x, fmaf(i0, vx, dv0));
        dv1 = fmaf(i2, ue.y, fmaf(i0, vy, dv1));
        dv2 = fmaf(i2, ue.z, fmaf(i0, vz, dv2));
    }

    ST<F32>(out, (size_t)i * FEAT + f, ds);
    const size_t ob = (size_t)nN * FEAT + ((size_t)i * FEAT + f) * 3;
    ST<F32>(out, ob + 0, dv0);
    ST<F32>(out, ob + 1, dv1);
    ST<F32>(out, ob + 2, dv2);
}

__global__ __launch_bounds__(128) void msg_a_kernel(const bf16* ws_w, const bf16* phi,
        const void* v_j, const int* src_ids, const float4* u_env, const int* offsets,
        const int* __restrict__ flags, void* out, int nE, int nN) {
    if (flags[0]) msg_a_body<1>(ws_w, phi, v_j, src_ids, u_env, offsets, out, nE, nN);
    else          msg_a_body<0>(ws_w, phi, v_j, src_ids, u_env, offsets, out, nE, nN);
}

// ---------- mode C message: table-lerp w_s + 12B packed gather; u4 precomputed ----------
template<int F32>
__device__ void msg_c_body(const unsigned short* __restrict__ tab, const bf16* __restrict__ rec,
        const float4* __restrict__ u4, const int* __restrict__ src_ids,
        const int* __restrict__ offsets, void* __restrict__ out, int nE, int nN) {
    const int i = blockIdx.x;
    const int f = threadIdx.x;
    int start = offsets[i];
    int end   = offsets[i + 1];
    if (start < 0) start = 0;
    if (end > nE) end = nE;

    float ds = 0.f, dv0 = 0.f, dv1 = 0.f, dv2 = 0.f;

    for (int p = start; p < end; ++p) {
        const int j = src_ids[p];
        const float4 uu = u4[p];           // uniform -> s_load
        const float binf = uu.w;
        int bin = (int)binf;
        if (bin > NB - 2) bin = NB - 2;
        const float fr = binf - (float)bin;
        const float m = (binf < (float)(NB - 1)) ? 1.0f : 0.0f;   // d < CUTOFF

        const unsigned short* T = tab + (size_t)bin * 384;
        const float t00 = us2f(T[f]);
        const float t01 = us2f(T[384 + f]);
        const float t10 = us2f(T[FEAT + f]);
        const float t11 = us2f(T[384 + FEAT + f]);
        const float t20 = us2f(T[2 * FEAT + f]);
        const float t21 = us2f(T[384 + 2 * FEAT + f]);
        const float w0 = fmaf(t01 - t00, fr, t00) * m;
        const float w1 = fmaf(t11 - t10, fr, t10) * m;
        const float w2 = fmaf(t21 - t20, fr, t20) * m;

        // 12B gather: {phi0,phi1,phi2,vx,vy,vz} bf16, 4B-aligned
        const unsigned* rp = (const unsigned*)(rec + ((size_t)j * FEAT + f) * 6);
        const unsigned ra = rp[0];
        const unsigned rb = rp[1];
        const unsigned rc = rp[2];
        const float p0 = __uint_as_float(ra << 16);
        const float p1 = __uint_as_float(ra & 0xffff0000u);
        const float p2 = __uint_as_float(rb << 16);
        const float vx = __uint_as_float(rb & 0xffff0000u);
        const float vy = __uint_as_float(rc << 16);
        const float vz = __uint_as_float(rc & 0xffff0000u);

        const float i0 = w0 * p0;
        const float i1 = w1 * p1;
        const float i2 = w2 * p2;
        ds += i1;
        dv0 = fmaf(i2, uu.x, fmaf(i0, vx, dv0));
        dv1 = fmaf(i2, uu.y, fmaf(i0, vy, dv1));
        dv2 = fmaf(i2, uu.z, fmaf(i0, vz, dv2));
    }

    ST<F32>(out, (size_t)i * FEAT + f, ds);
    const size_t ob = (size_t)nN * FEAT + ((size_t)i * FEAT + f) * 3;
    ST<F32>(out, ob + 0, dv0);
    ST<F32>(out, ob + 1, dv1);
    ST<F32>(out, ob + 2, dv2);
}

__global__ __launch_bounds__(128) void msg_c_kernel(const unsigned short* tab, const bf16* rec,
        const float4* u4, const int* src_ids, const int* offsets,
        const int* __restrict__ flags, void* out, int nE, int nN) {
    if (flags[0]) msg_c_body<1>(tab, rec, u4, src_ids, offsets, out, nE, nN);
    else          msg_c_body<0>(tab, rec, u4, src_ids, offsets, out, nE, nN);
}

// ---------- mode B message (fallback) ----------
template<int F32>
__device__ void msg_b_body(const void* __restrict__ v_j, const void* __restrict__ Wd,
        const void* __restrict__ bd, const bf16* __restrict__ phi,
        const float* __restrict__ gbuf, const int* __restrict__ src_ids,
        const float4* __restrict__ u_env, const int* __restrict__ offsets,
        void* __restrict__ out, int nE, int nN) {
    const int i = blockIdx.x;
    const int f = threadIdx.x;

    float wd0[NRBF], wd1[NRBF], wd2[NRBF];
    #pragma unroll
    for (int k = 0; k < NRBF; ++k) {
        wd0[k] = LD<F32>(Wd, (size_t)k * 384 + f);
        wd1[k] = LD<F32>(Wd, (size_t)k * 384 + FEAT + f);
        wd2[k] = LD<F32>(Wd, (size_t)k * 384 + 2 * FEAT + f);
    }
    const float bd0 = LD<F32>(bd, f);
    const float bd1 = LD<F32>(bd, FEAT + f);
    const float bd2 = LD<F32>(bd, 2 * FEAT + f);

    int start = offsets[i];
    int end   = offsets[i + 1];
    if (start < 0) start = 0;
    if (end > nE) end = nE;

    float ds = 0.f, dv0 = 0.f, dv1 = 0.f, dv2 = 0.f;

    for (int p = start; p < end; ++p) {
        const int j = src_ids[p];
        const float4 ue = u_env[p];
        const float* g = gbuf + (size_t)p * NRBF;
        float t0 = 0.f, t1 = 0.f, t2 = 0.f;
        #pragma unroll
        for (int k = 0; k < NRBF; ++k) {
            const float gk = g[k];
            t0 = fmaf(gk, wd0[k], t0);
            t1 = fmaf(gk, wd1[k], t1);
            t2 = fmaf(gk, wd2[k], t2);
        }
        const float w0 = fmaf(bd0, ue.w, t0);
        const float w1 = fmaf(bd1, ue.w, t1);
        const float w2 = fmaf(bd2, ue.w, t2);

        const bf16* ph = phi + (size_t)j * 384;
        const float p0 = b2f(ph[f]);
        const float p1 = b2f(ph[FEAT + f]);
        const float p2 = b2f(ph[2 * FEAT + f]);
        const float vx = LD<F32>(v_j, ((size_t)j * FEAT + f) * 3 + 0);
        const float vy = LD<F32>(v_j, ((size_t)j * FEAT + f) * 3 + 1);
        const float vz = LD<F32>(v_j, ((size_t)j * FEAT + f) * 3 + 2);

        const float i0 = w0 * p0;
        const float i1 = w1 * p1;
        const float i2 = w2 * p2;
        ds += i1;
        dv0 = fmaf(i2, ue.x, fmaf(i0, vx, dv0));
        dv1 = fmaf(i2, ue.y, fmaf(i0, vy, dv1));
        dv2 = fmaf(i2, ue.z, fmaf(i0, vz, dv2));
    }

    ST<F32>(out, (size_t)i * FEAT + f, ds);
    const size_t ob = (size_t)nN * FEAT + ((size_t)i * FEAT + f) * 3;
    ST<F32>(out, ob + 0, dv0);
    ST<F32>(out, ob + 1, dv1);
    ST<F32>(out, ob + 2, dv2);
}

__global__ __launch_bounds__(128) void msg_b_kernel(const void* v_j, const void* Wd,
        const void* bd, const bf16* phi, const float* gbuf, const int* src_ids,
        const float4* u_env, const int* offsets, const int* __restrict__ flags,
        void* out, int nE, int nN) {
    if (flags[0]) msg_b_body<1>(v_j, Wd, bd, phi, gbuf, src_ids, u_env, offsets, out, nE, nN);
    else          msg_b_body<0>(v_j, Wd, bd, phi, gbuf, src_ids, u_env, offsets, out, nE, nN);
}

extern "C" void kernel_launch(void* const* d_in, const int* in_sizes, int n_in,
                              void* d_out, int out_size, void* d_ws, size_t ws_size,
                              hipStream_t stream) {
    const void* s_j  = d_in[0];
    const void* v_j  = d_in[1];
    const void* r_ij = d_in[2];
    const int*  nbrs = (const int*)d_in[3];
    const void* W1   = d_in[4];
    const void* b1   = d_in[5];
    const void* W2   = d_in[6];
    const void* b2   = d_in[7];
    const void* Wd   = d_in[8];
    const void* bd   = d_in[9];

    const int nN = out_size / (4 * FEAT);   // 20000
    const int nE = in_sizes[2] / 3;         // 640000

    char* ws = (char*)d_ws;
    size_t off = 0;
    auto alloc = [&](size_t bytes) -> void* {
        void* p = ws + off;
        off = (off + bytes + 255) & ~(size_t)255;
        return p;
    };
    int*    flags    = (int*)alloc(16);
    int*    counts   = (int*)alloc((size_t)nN * 4);
    int*    offsets  = (int*)alloc(((size_t)nN + 1) * 4);
    int*    cursor   = (int*)alloc((size_t)nN * 4);
    int*    src_ids  = (int*)alloc((size_t)nE * 4);
    float4* u_env    = (float4*)alloc((size_t)nE * 16);
    float*  WdT      = (float*)alloc((size_t)384 * 24 * 4);
    const size_t base = off;

    // mode A layout: pos_of_e | phi | ws_w
    size_t offA = base;
    int*  pos_of_e = (int*)(ws + offA);  offA += ((size_t)nE * 4 + 255) & ~(size_t)255;
    bf16* phiA     = (bf16*)(ws + offA); offA += ((size_t)nN * 384 * 2 + 255) & ~(size_t)255;
    bf16* ws_w     = (bf16*)(ws + offA); offA += (size_t)nE * 384 * 2;
    // mode C layout: rec (12B per (node,f)) | tab
    size_t offC = base;
    bf16* rec = (bf16*)(ws + offC);      offC += ((size_t)nN * FEAT * 6 * 2 + 255) & ~(size_t)255;
    bf16* tab = (bf16*)(ws + offC);      offC += (size_t)NB * 384 * 2;
    // mode B layout: gbuf | phi
    size_t offB = base;
    float* gbufB = (float*)(ws + offB);  offB += ((size_t)nE * NRBF * 4 + 255) & ~(size_t)255;
    bf16*  phiB  = (bf16*)(ws + offB);   offB += (size_t)nN * 384 * 2;

    const int modeA = (ws_size >= offA) ? 1 : 0;
    const int modeC = (!modeA && ws_size >= offC) ? 1 : 0;

    init_kernel<<<(nN + 255) / 256, 256, 0, stream>>>(s_j, nbrs, nE, flags, counts, nN);
    hist_kernel<<<(nE + 255) / 256, 256, 0, stream>>>(nbrs, flags, counts, nE, nN);
    scan_kernel<<<1, 1024, 0, stream>>>(counts, offsets, cursor, nN);

    const int psMode = modeA ? 1 : (modeC ? 2 : 0);
    pre_scatter_kernel<<<(nE + 255) / 256, 256, 0, stream>>>(
        r_ij, nbrs, flags, cursor, src_ids, u_env, pos_of_e, gbufB, nE, nN, psMode);

    if (modeA) {
        prep_kernel<<<1, 384, 0, stream>>>(Wd, bd, WdT, flags);
        gemm_node_kernel<<<(nN + 7) / 8, 384, 0, stream>>>(s_j, v_j, W1, b1, W2, b2, phiA, flags, nN, 0);
        pre_ws_kernel<<<(nE + 255) / 256, 256, 0, stream>>>(r_ij, WdT, pos_of_e, ws_w, flags, nE);
        msg_a_kernel<<<nN, 128, 0, stream>>>(ws_w, phiA, v_j, src_ids, u_env, offsets,
                                             flags, d_out, nE, nN);
    } else if (modeC) {
        build_table_kernel<<<NB, 384, 0, stream>>>(Wd, bd, tab, flags);
        gemm_node_kernel<<<(nN + 7) / 8, 384, 0, stream>>>(s_j, v_j, W1, b1, W2, b2, rec, flags, nN, 1);
        msg_c_kernel<<<nN, 128, 0, stream>>>((const unsigned short*)tab, rec, u_env, src_ids,
                                             offsets, flags, d_out, nE, nN);
    } else {
        gemm_node_kernel<<<(nN + 7) / 8, 384, 0, stream>>>(s_j, v_j, W1, b1, W2, b2, phiB, flags, nN, 0);
        msg_b_kernel<<<nN, 128, 0, stream>>>(v_j, Wd, bd, phiB, gbufB, src_ids, u_env,
                                             offsets, flags, d_out, nE, nN);
    }
}